// Round 5
// baseline (14161.722 us; speedup 1.0000x reference)
//
#include <hip/hip_runtime.h>
#include <cstdint>
#include <cstddef>

#define B_ 512
#define S_ 336
#define F_ 16
#define H_ 256
#define P_ 48

typedef __bf16 bhalf;

// ---------------------------------------------------------------------------
// Encoder: self-contained blocks, NO inter-block communication.
// 128 blocks x 256 threads; block owns 4 batch rows for the whole scan.
// Thread jj computes gate-rows {jj, 256+jj, 512+jj} for all 4 rows.
// h in LDS (fp32); enc_out stored bf16 (used only by attention combine);
// final h stored fp32 into hcur (the decoder's initial hidden state).
// ---------------------------------------------------------------------------
__global__ __launch_bounds__(256) void enc_kernel(
    const float* __restrict__ Whh, const float* __restrict__ Wih,
    const float* __restrict__ bih, const float* __restrict__ bhh,
    const float* __restrict__ xb,      // [B][S][F]
    bhalf* __restrict__ enc_out,       // [B][S][H] bf16
    float* __restrict__ hcur)          // [B][H] fp32
{
  __shared__ float hld[4][260];
  __shared__ float xld[4][16];
  const int tid = threadIdx.x;
  const int jj  = tid;
  const int b0  = blockIdx.x * 4;

  for (int e = tid; e < 4 * 260; e += 256) ((float*)hld)[e] = 0.0f;
  __syncthreads();

  const float4* wR4 = (const float4*)(Whh + (size_t)jj * 256);
  const float4* wZ4 = (const float4*)(Whh + (size_t)(256 + jj) * 256);
  const float4* wN4 = (const float4*)(Whh + (size_t)(512 + jj) * 256);
  const float*  wiR = Wih + (size_t)jj * 16;
  const float*  wiZ = Wih + (size_t)(256 + jj) * 16;
  const float*  wiN = Wih + (size_t)(512 + jj) * 16;
  const float bRv = bih[jj]       + bhh[jj];
  const float bZv = bih[256 + jj] + bhh[256 + jj];
  const float bNx = bih[512 + jj];
  const float bNh = bhh[512 + jj];

  for (int t = 0; t < S_; ++t) {
    if (tid < 64) {
      const int row = tid >> 4, f = tid & 15;
      xld[row][f] = xb[((size_t)(b0 + row) * S_ + t) * F_ + f];
    }
    __syncthreads();

    float aR[4], aZ[4], aNh[4], aNx[4];
#pragma unroll
    for (int rr = 0; rr < 4; ++rr) {
      aR[rr] = bRv; aZ[rr] = bZv; aNh[rr] = bNh; aNx[rr] = bNx;
    }
#pragma unroll
    for (int f = 0; f < 16; ++f) {
      const float wr = wiR[f], wz = wiZ[f], wn = wiN[f];
#pragma unroll
      for (int rr = 0; rr < 4; ++rr) {
        const float xv = xld[rr][f];
        aR[rr]  += wr * xv;
        aZ[rr]  += wz * xv;
        aNx[rr] += wn * xv;
      }
    }
#pragma unroll 4
    for (int k4 = 0; k4 < 64; ++k4) {
      const float4 wr = wR4[k4];
      const float4 wz = wZ4[k4];
      const float4 wn = wN4[k4];
#pragma unroll
      for (int rr = 0; rr < 4; ++rr) {
        const float4 hv = *(const float4*)&hld[rr][k4 * 4];
        aR[rr]  += wr.x * hv.x + wr.y * hv.y + wr.z * hv.z + wr.w * hv.w;
        aZ[rr]  += wz.x * hv.x + wz.y * hv.y + wz.z * hv.z + wz.w * hv.w;
        aNh[rr] += wn.x * hv.x + wn.y * hv.y + wn.z * hv.z + wn.w * hv.w;
      }
    }

    float hnew[4];
#pragma unroll
    for (int rr = 0; rr < 4; ++rr) {
      const float r = 1.0f / (1.0f + expf(-aR[rr]));
      const float z = 1.0f / (1.0f + expf(-aZ[rr]));
      const float n = tanhf(aNx[rr] + r * aNh[rr]);
      hnew[rr] = (1.0f - z) * n + z * hld[rr][jj];
    }
    __syncthreads();
#pragma unroll
    for (int rr = 0; rr < 4; ++rr) {
      hld[rr][jj] = hnew[rr];
      enc_out[((size_t)(b0 + rr) * S_ + t) * H_ + jj] = (bhalf)hnew[rr];
    }
    __syncthreads();
  }

#pragma unroll
  for (int rr = 0; rr < 4; ++rr)
    hcur[(size_t)(b0 + rr) * H_ + jj] = hld[rr][jj];
}

// ---------------------------------------------------------------------------
// y0 = xb[:, -1, :]
// ---------------------------------------------------------------------------
__global__ __launch_bounds__(256) void y0_kernel(const float* __restrict__ xb,
                                                 float* __restrict__ ycur) {
  const int idx = blockIdx.x * 256 + threadIdx.x;
  if (idx < B_ * F_) {
    const int b = idx >> 4, f = idx & 15;
    ycur[idx] = xb[((size_t)b * S_ + (S_ - 1)) * F_ + f];
  }
}

// ---------------------------------------------------------------------------
// One decoder step (launched 48x). Fully block-local: 128 blocks x 256 thr,
// block owns 4 batch rows. Phases: attention scores -> softmax -> combine
// (bf16 enc_out) -> GRU -> out (y feedback) -> pred write.
// hcur/ycur updated in place (kernel boundary orders steps).
// ---------------------------------------------------------------------------
__global__ __launch_bounds__(256) void dec_step_kernel(
    const int p,
    const float* __restrict__ Whh, const float* __restrict__ Wih,
    const float* __restrict__ bih, const float* __restrict__ bhh,
    const float* __restrict__ attW, const float* __restrict__ attb,
    const float* __restrict__ outW, const float* __restrict__ outb,
    const float* __restrict__ linW, const float* __restrict__ linb,
    const bhalf* __restrict__ enc_out,
    float* __restrict__ hcur, float* __restrict__ ycur,
    float* __restrict__ dout)
{
  __shared__ float hL[4][260];
  __shared__ float cL[4][260];
  __shared__ float sc[4][S_];
  __shared__ float yL[4][16];
  __shared__ float oL[4][16];
  const int tid  = threadIdx.x;
  const int lane = tid & 63;
  const int wv   = tid >> 6;
  const int b0   = blockIdx.x * 4;

  for (int e = tid; e < 4 * 256; e += 256)
    hL[e >> 8][e & 255] = hcur[(size_t)(b0 + (e >> 8)) * H_ + (e & 255)];
  if (tid < 64)
    yL[tid >> 4][tid & 15] = ycur[(size_t)(b0 + (tid >> 4)) * F_ + (tid & 15)];
  __syncthreads();

  // ---- attention scores: sc[r][s] = attW[s]·[h_r | y_r] + attb[s] ----
  for (int e = tid; e < 4 * S_; e += 256) {
    const int r = e / S_, s = e - r * S_;
    const float4* w4 = (const float4*)(attW + (size_t)s * 272);
    const float4* h4 = (const float4*)hL[r];    // row base 260 floats: 16B-aligned
    float d = attb[s];
#pragma unroll 4
    for (int k4 = 0; k4 < 64; ++k4) {
      const float4 w = w4[k4], h = h4[k4];
      d += w.x * h.x + w.y * h.y + w.z * h.z + w.w * h.w;
    }
    const float* wy = attW + (size_t)s * 272 + 256;
#pragma unroll
    for (int f = 0; f < 16; ++f) d += wy[f] * yL[r][f];
    sc[r][s] = d;
  }
  __syncthreads();

  // ---- softmax per row: wave wv handles row wv ----
  {
    const int r = wv;
    float mx = -3e38f;
    for (int s = lane; s < S_; s += 64) mx = fmaxf(mx, sc[r][s]);
#pragma unroll
    for (int o = 32; o > 0; o >>= 1) mx = fmaxf(mx, __shfl_xor(mx, o, 64));
    float sum = 0.0f;
    for (int s = lane; s < S_; s += 64) {
      const float e = expf(sc[r][s] - mx);
      sc[r][s] = e;
      sum += e;
    }
#pragma unroll
    for (int o = 32; o > 0; o >>= 1) sum += __shfl_xor(sum, o, 64);
    const float inv = 1.0f / sum;
    for (int s = lane; s < S_; s += 64) sc[r][s] *= inv;
  }
  __syncthreads();

  // ---- combine: cL[r][i] = sum_s sc[r][s] * enc_out[b0+r][s][i] ----
  {
    const int i = tid;   // H == 256
#pragma unroll
    for (int r = 0; r < 4; ++r) {
      const bhalf* ep = enc_out + (size_t)(b0 + r) * S_ * H_ + i;
      float acc = 0.0f;
      int s = 0;
      for (; s + 4 <= S_; s += 4) {
        acc += sc[r][s]     * (float)ep[(size_t)(s)     * H_];
        acc += sc[r][s + 1] * (float)ep[(size_t)(s + 1) * H_];
        acc += sc[r][s + 2] * (float)ep[(size_t)(s + 2) * H_];
        acc += sc[r][s + 3] * (float)ep[(size_t)(s + 3) * H_];
      }
      cL[r][i] = acc;
    }
  }
  __syncthreads();

  // ---- GRU: thread jj computes gate rows {jj, 256+jj, 512+jj} ----
  const int jj = tid;
  float aR[4], aZ[4], aNh[4], aNx[4];
  {
    const float bRv = bih[jj]       + bhh[jj];
    const float bZv = bih[256 + jj] + bhh[256 + jj];
    const float bNxv = bih[512 + jj];
    const float bNhv = bhh[512 + jj];
#pragma unroll
    for (int rr = 0; rr < 4; ++rr) {
      aR[rr] = bRv; aZ[rr] = bZv; aNh[rr] = bNhv; aNx[rr] = bNxv;
    }
  }
  {
    const float4* whR = (const float4*)(Whh + (size_t)jj * 256);
    const float4* whZ = (const float4*)(Whh + (size_t)(256 + jj) * 256);
    const float4* whN = (const float4*)(Whh + (size_t)(512 + jj) * 256);
    const float4* wiR = (const float4*)(Wih + (size_t)jj * 256);
    const float4* wiZ = (const float4*)(Wih + (size_t)(256 + jj) * 256);
    const float4* wiN = (const float4*)(Wih + (size_t)(512 + jj) * 256);
#pragma unroll 4
    for (int k4 = 0; k4 < 64; ++k4) {
      const float4 hr = whR[k4], hz = whZ[k4], hn = whN[k4];
      const float4 ir = wiR[k4], iz = wiZ[k4], in_ = wiN[k4];
#pragma unroll
      for (int rr = 0; rr < 4; ++rr) {
        const float4 hv = *(const float4*)&hL[rr][k4 * 4];
        const float4 cv = *(const float4*)&cL[rr][k4 * 4];
        aR[rr]  += hr.x * hv.x + hr.y * hv.y + hr.z * hv.z + hr.w * hv.w
                 + ir.x * cv.x + ir.y * cv.y + ir.z * cv.z + ir.w * cv.w;
        aZ[rr]  += hz.x * hv.x + hz.y * hv.y + hz.z * hv.z + hz.w * hv.w
                 + iz.x * cv.x + iz.y * cv.y + iz.z * cv.z + iz.w * cv.w;
        aNh[rr] += hn.x * hv.x + hn.y * hv.y + hn.z * hv.z + hn.w * hv.w;
        aNx[rr] += in_.x * cv.x + in_.y * cv.y + in_.z * cv.z + in_.w * cv.w;
      }
    }
  }

  float h2v[4];
#pragma unroll
  for (int rr = 0; rr < 4; ++rr) {
    const float r = 1.0f / (1.0f + expf(-aR[rr]));
    const float z = 1.0f / (1.0f + expf(-aZ[rr]));
    const float n = tanhf(aNx[rr] + r * aNh[rr]);
    h2v[rr] = (1.0f - z) * n + z * hL[rr][jj];
  }
  __syncthreads();   // all reads of old hL complete
#pragma unroll
  for (int rr = 0; rr < 4; ++rr) {
    hL[rr][jj] = h2v[rr];
    hcur[(size_t)(b0 + rr) * H_ + jj] = h2v[rr];
  }
  __syncthreads();

  // ---- out = h2 @ outW.T + outb ; y feedback ----
  if (tid < 64) {
    const int r = tid >> 4, f = tid & 15;
    const float* wr = outW + (size_t)f * H_;
    const float* hrow = hL[r];
    float o = outb[f];
    for (int k = 0; k < H_; ++k) o += hrow[k] * wr[k];
    oL[r][f] = o;
    ycur[(size_t)(b0 + r) * F_ + f] = o;
  }
  __syncthreads();

  // ---- pred[b][p] = out·linW + linb ----
  if (tid < 4) {
    float pr = linb[0];
#pragma unroll
    for (int f = 0; f < 16; ++f) pr += oL[tid][f] * linW[f];
    dout[(size_t)(b0 + tid) * P_ + p] = pr;
  }
}

// ---------------------------------------------------------------------------
extern "C" void kernel_launch(void* const* d_in, const int* in_sizes, int n_in,
                              void* d_out, int out_size, void* d_ws, size_t ws_size,
                              hipStream_t stream)
{
  (void)in_sizes; (void)n_in; (void)out_size;
  const float* xb      = (const float*)d_in[0];
  const float* enc_Wih = (const float*)d_in[1];
  const float* enc_Whh = (const float*)d_in[2];
  const float* enc_bih = (const float*)d_in[3];
  const float* enc_bhh = (const float*)d_in[4];
  const float* att_W   = (const float*)d_in[5];
  const float* att_b   = (const float*)d_in[6];
  const float* dec_Wih = (const float*)d_in[7];
  const float* dec_Whh = (const float*)d_in[8];
  const float* dec_bih = (const float*)d_in[9];
  const float* dec_bhh = (const float*)d_in[10];
  const float* out_W   = (const float*)d_in[11];
  const float* out_b   = (const float*)d_in[12];
  const float* lin_W   = (const float*)d_in[13];
  const float* lin_b   = (const float*)d_in[14];
  float* dout = (float*)d_out;

  char* ws = (char*)d_ws;
  const size_t off_enc = 0;                                    // bf16 enc_out
  const size_t off_hc  = off_enc + (size_t)B_ * S_ * H_ * 2;   // 88,080,384
  const size_t off_yc  = off_hc + (size_t)B_ * H_ * 4;
  const size_t need    = off_yc + (size_t)B_ * F_ * 4;
  if (ws_size < need) return;

  bhalf* enc_out = (bhalf*)(ws + off_enc);
  float* hcur    = (float*)(ws + off_hc);
  float* ycur    = (float*)(ws + off_yc);

  enc_kernel<<<B_ / 4, 256, 0, stream>>>(enc_Whh, enc_Wih, enc_bih, enc_bhh,
                                         xb, enc_out, hcur);
  y0_kernel<<<(B_ * F_ + 255) / 256, 256, 0, stream>>>(xb, ycur);
  for (int p = 0; p < P_; ++p) {
    dec_step_kernel<<<B_ / 4, 256, 0, stream>>>(
        p, dec_Whh, dec_Wih, dec_bih, dec_bhh, att_W, att_b,
        out_W, out_b, lin_W, lin_b, enc_out, hcur, ycur, dout);
  }
}

// Round 6
// 9140.635 us; speedup vs baseline: 1.5493x; 1.5493x over previous
//
#include <hip/hip_runtime.h>
#include <cstdint>
#include <cstddef>

#define B_ 512
#define S_ 336
#define F_ 16
#define H_ 256
#define P_ 48
#define DR_ 2              // batch rows per decoder block

typedef __bf16 bhalf;
typedef __attribute__((ext_vector_type(8))) __bf16 bhalf8;
typedef __attribute__((ext_vector_type(4))) float f32x4;

#define MFMA16(A, Bv, C) __builtin_amdgcn_mfma_f32_16x16x32_bf16((A), (Bv), (C), 0, 0, 0)

__device__ __forceinline__ float fastrcp(float x) { return __builtin_amdgcn_rcpf(x); }
__device__ __forceinline__ float sigm(float x) { return fastrcp(1.0f + __expf(-x)); }
__device__ __forceinline__ float tanh_f(float x) { return 2.0f * fastrcp(1.0f + __expf(-2.0f * x)) - 1.0f; }

__device__ __forceinline__ bhalf8 bzero8() {
  bhalf8 v;
#pragma unroll
  for (int j = 0; j < 8; ++j) v[j] = (bhalf)0.0f;
  return v;
}

// ---------------------------------------------------------------------------
// Encoder: weight-stationary MFMA flag pipeline.
// 256 blocks x 128 threads (2 waves). 32 groups x 8 members; group owns a
// 16-batch tile, member w owns 32 gate-cols (16 per wave). K = 288:
// [h(256) | x(16) | pad]. bf16x3: Ah*Whi + Ah*Wlo + Al*Whi; Whi in regs,
// Wlo in LDS; h exact fp32 in registers (hold[]), published per step as
// bf16 hi+lo planes through L2 with agent-scope acquire/release flags.
// enc_out (hi plane) feeds the decoder's attention combine; hcur fp32 exact.
// ---------------------------------------------------------------------------
__global__ __launch_bounds__(128, 1) void enc_kernel(
    const float* __restrict__ Whh, const float* __restrict__ Wih,
    const float* __restrict__ bih, const float* __restrict__ bhh,
    const float* __restrict__ xb,        // [B][S][F] fp32
    bhalf* __restrict__ enc_out,         // [B][S][H]
    float* __restrict__ hcur,            // [B][H] final h, fp32 exact
    bhalf* __restrict__ hbuf_hi,         // [2][B][H]
    bhalf* __restrict__ hbuf_lo,         // [2][B][H]
    unsigned int* __restrict__ flags)    // [32][S]
{
  __shared__ bhalf lds_lo[54 * 64 * 8];          // lo-plane B-frags, both waves
  const bhalf8* lds_v = (const bhalf8*)lds_lo;

  const int tid  = threadIdx.x;
  const int lane = tid & 63;
  const int wv   = tid >> 6;
  const int ncol = lane & 15;
  const int quad = lane >> 4;

  const int blk = blockIdx.x;
  const int g   = (blk & 7) * 4 + (blk >> 6);   // group 0..31
  const int w   = (blk >> 3) & 7;               // member 0..7
  const int b0  = g * 16;
  const int iw0 = w * 32;                       // block's 32-col tile base
  const int i0  = iw0 + wv * 16;                // this wave's 16-col tile

  // ---- lo-plane B-frags into LDS: fi = (wv2*3 + gate)*9 + kt ----
  for (int it = tid; it < 54 * 64; it += 128) {
    const int fi = it >> 6;
    const int ln = it & 63;
    const int kt = fi % 9;
    const int rem = fi / 9;
    const int gg = rem % 3;
    const int wv2 = rem / 3;
    const int jrow = gg * 256 + iw0 + wv2 * 16 + (ln & 15);
    const int kbase = kt * 32 + ((ln >> 4) << 3);
    bhalf* dst = lds_lo + (size_t)it * 8;
#pragma unroll
    for (int j = 0; j < 8; ++j) {
      const int k = kbase + j;
      float v = 0.0f;
      if (k < 256) v = Whh[(size_t)jrow * 256 + k];
      else if (k < 272) v = Wih[(size_t)jrow * 16 + (k - 256)];
      const bhalf hi = (bhalf)v;
      dst[j] = (bhalf)(v - (float)hi);
    }
  }

  // ---- hi-plane B-frags in registers: B[k][n], n=lane&15 -> gate row ----
  bhalf8 bWh[3][9];
#pragma unroll
  for (int gg = 0; gg < 3; ++gg) {
    const int jrow = gg * 256 + i0 + ncol;
#pragma unroll
    for (int kt = 0; kt < 9; ++kt) {
      bhalf8 v = bzero8();
      if (kt < 8) {
        const float* src = Whh + (size_t)jrow * 256 + kt * 32 + quad * 8;
#pragma unroll
        for (int j = 0; j < 8; ++j) v[j] = (bhalf)src[j];
      } else if (quad < 2) {
        const float* src = Wih + (size_t)jrow * 16 + quad * 8;
#pragma unroll
        for (int j = 0; j < 8; ++j) v[j] = (bhalf)src[j];
      }
      bWh[gg][kt] = v;
    }
  }

  const int jr = i0 + ncol;
  const float bR  = bih[jr]       + bhh[jr];
  const float bZ  = bih[256 + jr] + bhh[256 + jr];
  const float bNx = bih[512 + jr];
  const float bNh = bhh[512 + jr];

  __syncthreads();

  const int bA = b0 + ncol;   // A-row (m = lane&15)
  const int kA = quad * 8;    // k offset in 32-wide tile

  float hold[4] = {0.0f, 0.0f, 0.0f, 0.0f};

  for (int t = 0; t < S_; ++t) {
    if (t > 0) {
      unsigned int* fp = &flags[g * S_ + (t - 1)];
      if (tid == 0) {
        while (__hip_atomic_load(fp, __ATOMIC_ACQUIRE, __HIP_MEMORY_SCOPE_AGENT) < 8u)
          __builtin_amdgcn_s_sleep(2);
      }
      __syncthreads();
      (void)__hip_atomic_load(fp, __ATOMIC_ACQUIRE, __HIP_MEMORY_SCOPE_AGENT);
    }

    // x hi/lo A-frags (fp32 source, split on the fly); k=256..271 -> quads 0,1
    bhalf8 xh = bzero8(), xl = bzero8();
    if (quad < 2) {
      const float* xp = xb + ((size_t)bA * S_ + t) * F_ + quad * 8;
#pragma unroll
      for (int j = 0; j < 8; ++j) {
        const float v = xp[j];
        const bhalf h = (bhalf)v;
        xh[j] = h;
        xl[j] = (bhalf)(v - (float)h);
      }
    }

    f32x4 aR0 = {0,0,0,0}, aR1 = {0,0,0,0}, aR2 = {0,0,0,0};
    f32x4 aZ0 = {0,0,0,0}, aZ1 = {0,0,0,0}, aZ2 = {0,0,0,0};
    f32x4 aN0 = {0,0,0,0}, aN1 = {0,0,0,0}, aN2 = {0,0,0,0};
    f32x4 aNx = {0,0,0,0};

    if (t > 0) {
      const int slot = (t - 1) & 1;
      const bhalf* hp = hbuf_hi + ((size_t)slot * B_ + bA) * H_ + kA;
      const bhalf* lp = hbuf_lo + ((size_t)slot * B_ + bA) * H_ + kA;
#pragma unroll
      for (int kt = 0; kt < 8; ++kt) {
        const bhalf8 Ah = *(const bhalf8*)(hp + kt * 32);
        const bhalf8 Al = *(const bhalf8*)(lp + kt * 32);
        const bhalf8 wl0 = lds_v[((wv * 3 + 0) * 9 + kt) * 64 + lane];
        const bhalf8 wl1 = lds_v[((wv * 3 + 1) * 9 + kt) * 64 + lane];
        const bhalf8 wl2 = lds_v[((wv * 3 + 2) * 9 + kt) * 64 + lane];
        aR0 = MFMA16(Ah, bWh[0][kt], aR0);
        aR1 = MFMA16(Ah, wl0, aR1);
        aR2 = MFMA16(Al, bWh[0][kt], aR2);
        aZ0 = MFMA16(Ah, bWh[1][kt], aZ0);
        aZ1 = MFMA16(Ah, wl1, aZ1);
        aZ2 = MFMA16(Al, bWh[1][kt], aZ2);
        aN0 = MFMA16(Ah, bWh[2][kt], aN0);
        aN1 = MFMA16(Ah, wl1 /*dummy keep reg*/, aN1), aN1 = aN1;  // no-op guard
        aN1 = MFMA16(Ah, wl2, aN1);
        aN2 = MFMA16(Al, bWh[2][kt], aN2);
      }
    }
    {  // kt = 8: x-part. R/Z join the gate accumulators; N x-part separate.
      const bhalf8 wl0 = lds_v[((wv * 3 + 0) * 9 + 8) * 64 + lane];
      const bhalf8 wl1 = lds_v[((wv * 3 + 1) * 9 + 8) * 64 + lane];
      const bhalf8 wl2 = lds_v[((wv * 3 + 2) * 9 + 8) * 64 + lane];
      aR0 = MFMA16(xh, bWh[0][8], aR0);
      aR1 = MFMA16(xh, wl0, aR1);
      aR2 = MFMA16(xl, bWh[0][8], aR2);
      aZ0 = MFMA16(xh, bWh[1][8], aZ0);
      aZ1 = MFMA16(xh, wl1, aZ1);
      aZ2 = MFMA16(xl, bWh[1][8], aZ2);
      aNx = MFMA16(xh, bWh[2][8], aNx);
      aNx = MFMA16(xh, wl2, aNx);
      aNx = MFMA16(xl, bWh[2][8], aNx);
    }

    // ---- gates + publish (C/D: col = lane&15, row = quad*4 + reg) ----
    const int iL = i0 + ncol;
#pragma unroll
    for (int r = 0; r < 4; ++r) {
      const int bb = b0 + quad * 4 + r;
      const float sR  = aR0[r] + aR1[r] + aR2[r] + bR;
      const float sZ  = aZ0[r] + aZ1[r] + aZ2[r] + bZ;
      const float nhv = aN0[r] + aN1[r] + aN2[r] + bNh;
      const float nxv = aNx[r] + bNx;
      const float rr = sigm(sR);
      const float zz = sigm(sZ);
      const float nn = tanh_f(nxv + rr * nhv);
      const float h2 = (1.0f - zz) * nn + zz * hold[r];
      hold[r] = h2;
      const bhalf hi = (bhalf)h2;
      const bhalf lo = (bhalf)(h2 - (float)hi);
      enc_out[((size_t)bb * S_ + t) * H_ + iL] = hi;
      hbuf_hi[((size_t)(t & 1) * B_ + bb) * H_ + iL] = hi;
      hbuf_lo[((size_t)(t & 1) * B_ + bb) * H_ + iL] = lo;
    }

    __syncthreads();   // compiler drains vmcnt(0) before s_barrier
    if (tid == 0) {
      __hip_atomic_fetch_add(&flags[g * S_ + t], 1u, __ATOMIC_RELEASE,
                             __HIP_MEMORY_SCOPE_AGENT);
    }
  }

  // final hidden state, exact fp32 from registers
#pragma unroll
  for (int r = 0; r < 4; ++r)
    hcur[(size_t)(b0 + quad * 4 + r) * H_ + i0 + ncol] = hold[r];
}

// ---------------------------------------------------------------------------
// Decoder: ONE fused persistent kernel, all 48 steps. 256 blocks x 256 thr,
// block owns DR_=2 batch rows end-to-end (h, y in LDS; zero cross-block deps).
// Per-step phase/barrier structure identical to the verified round-5 kernel.
// ---------------------------------------------------------------------------
__global__ __launch_bounds__(256) void dec_kernel(
    const float* __restrict__ Whh, const float* __restrict__ Wih,
    const float* __restrict__ bih, const float* __restrict__ bhh,
    const float* __restrict__ attW, const float* __restrict__ attb,
    const float* __restrict__ outW, const float* __restrict__ outb,
    const float* __restrict__ linW, const float* __restrict__ linb,
    const bhalf* __restrict__ enc_out, const float* __restrict__ hcur,
    const float* __restrict__ xb, float* __restrict__ dout)
{
  __shared__ float hL[DR_][260];
  __shared__ float cL[DR_][260];
  __shared__ float sc[DR_][S_];
  __shared__ float yL[DR_][16];
  __shared__ float oL[DR_][16];
  const int tid  = threadIdx.x;
  const int lane = tid & 63;
  const int wv   = tid >> 6;
  const int b0   = blockIdx.x * DR_;
  const int jj   = tid;

  for (int e = tid; e < DR_ * 256; e += 256)
    hL[e >> 8][e & 255] = hcur[(size_t)(b0 + (e >> 8)) * H_ + (e & 255)];
  if (tid < DR_ * 16)
    yL[tid >> 4][tid & 15] =
        xb[((size_t)(b0 + (tid >> 4)) * S_ + (S_ - 1)) * F_ + (tid & 15)];
  __syncthreads();

  // hoisted invariants
  const float bRv  = bih[jj]       + bhh[jj];
  const float bZv  = bih[256 + jj] + bhh[256 + jj];
  const float bNxv = bih[512 + jj];
  const float bNhv = bhh[512 + jj];
  const float4* whR = (const float4*)(Whh + (size_t)jj * 256);
  const float4* whZ = (const float4*)(Whh + (size_t)(256 + jj) * 256);
  const float4* whN = (const float4*)(Whh + (size_t)(512 + jj) * 256);
  const float4* wiR = (const float4*)(Wih + (size_t)jj * 256);
  const float4* wiZ = (const float4*)(Wih + (size_t)(256 + jj) * 256);
  const float4* wiN = (const float4*)(Wih + (size_t)(512 + jj) * 256);

  for (int p = 0; p < P_; ++p) {
    // ---- attention scores ----
    for (int e = tid; e < DR_ * S_; e += 256) {
      const int r = e / S_, s = e - r * S_;
      const float4* w4 = (const float4*)(attW + (size_t)s * 272);
      const float4* h4 = (const float4*)hL[r];
      float d = attb[s];
#pragma unroll 4
      for (int k4 = 0; k4 < 64; ++k4) {
        const float4 w = w4[k4], h = h4[k4];
        d += w.x * h.x + w.y * h.y + w.z * h.z + w.w * h.w;
      }
      const float* wy = attW + (size_t)s * 272 + 256;
#pragma unroll
      for (int f = 0; f < 16; ++f) d += wy[f] * yL[r][f];
      sc[r][s] = d;
    }
    __syncthreads();

    // ---- softmax (wave wv handles row wv) ----
    if (wv < DR_) {
      const int r = wv;
      float mx = -3e38f;
      for (int s = lane; s < S_; s += 64) mx = fmaxf(mx, sc[r][s]);
#pragma unroll
      for (int o = 32; o > 0; o >>= 1) mx = fmaxf(mx, __shfl_xor(mx, o, 64));
      float sum = 0.0f;
      for (int s = lane; s < S_; s += 64) {
        const float e = expf(sc[r][s] - mx);
        sc[r][s] = e;
        sum += e;
      }
#pragma unroll
      for (int o = 32; o > 0; o >>= 1) sum += __shfl_xor(sum, o, 64);
      const float inv = 1.0f / sum;
      for (int s = lane; s < S_; s += 64) sc[r][s] *= inv;
    }
    __syncthreads();

    // ---- combine ----
    {
      const int i = tid;   // H == 256
#pragma unroll
      for (int r = 0; r < DR_; ++r) {
        const bhalf* ep = enc_out + (size_t)(b0 + r) * S_ * H_ + i;
        float acc = 0.0f;
        int s = 0;
        for (; s + 4 <= S_; s += 4) {
          acc += sc[r][s]     * (float)ep[(size_t)(s)     * H_];
          acc += sc[r][s + 1] * (float)ep[(size_t)(s + 1) * H_];
          acc += sc[r][s + 2] * (float)ep[(size_t)(s + 2) * H_];
          acc += sc[r][s + 3] * (float)ep[(size_t)(s + 3) * H_];
        }
        cL[r][i] = acc;
      }
    }
    __syncthreads();

    // ---- GRU ----
    float aR[DR_], aZ[DR_], aNh[DR_], aNx[DR_];
#pragma unroll
    for (int rr = 0; rr < DR_; ++rr) {
      aR[rr] = bRv; aZ[rr] = bZv; aNh[rr] = bNhv; aNx[rr] = bNxv;
    }
#pragma unroll 4
    for (int k4 = 0; k4 < 64; ++k4) {
      const float4 hr = whR[k4], hz = whZ[k4], hn = whN[k4];
      const float4 ir = wiR[k4], iz = wiZ[k4], in_ = wiN[k4];
#pragma unroll
      for (int rr = 0; rr < DR_; ++rr) {
        const float4 hv = *(const float4*)&hL[rr][k4 * 4];
        const float4 cv = *(const float4*)&cL[rr][k4 * 4];
        aR[rr]  += hr.x * hv.x + hr.y * hv.y + hr.z * hv.z + hr.w * hv.w
                 + ir.x * cv.x + ir.y * cv.y + ir.z * cv.z + ir.w * cv.w;
        aZ[rr]  += hz.x * hv.x + hz.y * hv.y + hz.z * hv.z + hz.w * hv.w
                 + iz.x * cv.x + iz.y * cv.y + iz.z * cv.z + iz.w * cv.w;
        aNh[rr] += hn.x * hv.x + hn.y * hv.y + hn.z * hv.z + hn.w * hv.w;
        aNx[rr] += in_.x * cv.x + in_.y * cv.y + in_.z * cv.z + in_.w * cv.w;
      }
    }

    float h2v[DR_];
#pragma unroll
    for (int rr = 0; rr < DR_; ++rr) {
      const float r = 1.0f / (1.0f + expf(-aR[rr]));
      const float z = 1.0f / (1.0f + expf(-aZ[rr]));
      const float n = tanhf(aNx[rr] + r * aNh[rr]);
      h2v[rr] = (1.0f - z) * n + z * hL[rr][jj];
    }
    __syncthreads();   // all reads of old hL done
#pragma unroll
    for (int rr = 0; rr < DR_; ++rr) hL[rr][jj] = h2v[rr];
    __syncthreads();

    // ---- out + y feedback ----
    if (tid < DR_ * 16) {
      const int r = tid >> 4, f = tid & 15;
      const float* wr = outW + (size_t)f * H_;
      const float* hrow = hL[r];
      float o = outb[f];
      for (int k = 0; k < H_; ++k) o += hrow[k] * wr[k];
      oL[r][f] = o;
      yL[r][f] = o;
    }
    __syncthreads();

    // ---- pred ----
    if (tid < DR_) {
      float pr = linb[0];
#pragma unroll
      for (int f = 0; f < 16; ++f) pr += oL[tid][f] * linW[f];
      dout[(size_t)(b0 + tid) * P_ + p] = pr;
    }
    __syncthreads();
  }
}

// ---------------------------------------------------------------------------
extern "C" void kernel_launch(void* const* d_in, const int* in_sizes, int n_in,
                              void* d_out, int out_size, void* d_ws, size_t ws_size,
                              hipStream_t stream)
{
  (void)in_sizes; (void)n_in; (void)out_size;
  const float* xb      = (const float*)d_in[0];
  const float* enc_Wih = (const float*)d_in[1];
  const float* enc_Whh = (const float*)d_in[2];
  const float* enc_bih = (const float*)d_in[3];
  const float* enc_bhh = (const float*)d_in[4];
  const float* att_W   = (const float*)d_in[5];
  const float* att_b   = (const float*)d_in[6];
  const float* dec_Wih = (const float*)d_in[7];
  const float* dec_Whh = (const float*)d_in[8];
  const float* dec_bih = (const float*)d_in[9];
  const float* dec_bhh = (const float*)d_in[10];
  const float* out_W   = (const float*)d_in[11];
  const float* out_b   = (const float*)d_in[12];
  const float* lin_W   = (const float*)d_in[13];
  const float* lin_b   = (const float*)d_in[14];
  float* dout = (float*)d_out;

  char* ws = (char*)d_ws;
  const size_t off_enc = 0;                                      // bf16 enc_out
  const size_t off_hbh = off_enc + (size_t)B_ * S_ * H_ * 2;     // 88,080,384
  const size_t off_hbl = off_hbh + (size_t)2 * B_ * H_ * 2;
  const size_t off_hc  = off_hbl + (size_t)2 * B_ * H_ * 2;
  const size_t off_fl  = off_hc + (size_t)B_ * H_ * 4;
  const size_t need    = off_fl + 32 * S_ * sizeof(unsigned int);
  if (ws_size < need) return;

  bhalf* enc_out = (bhalf*)(ws + off_enc);
  bhalf* hbuf_hi = (bhalf*)(ws + off_hbh);
  bhalf* hbuf_lo = (bhalf*)(ws + off_hbl);
  float* hcur    = (float*)(ws + off_hc);
  unsigned int* flags = (unsigned int*)(ws + off_fl);

  (void)hipMemsetAsync(flags, 0, 32 * S_ * sizeof(unsigned int), stream);
  enc_kernel<<<256, 128, 0, stream>>>(enc_Whh, enc_Wih, enc_bih, enc_bhh, xb,
                                      enc_out, hcur, hbuf_hi, hbuf_lo, flags);
  dec_kernel<<<B_ / DR_, 256, 0, stream>>>(dec_Whh, dec_Wih, dec_bih, dec_bhh,
                                           att_W, att_b, out_W, out_b,
                                           lin_W, lin_b, enc_out, hcur, xb, dout);
}

// Round 7
// 5493.857 us; speedup vs baseline: 2.5777x; 1.6638x over previous
//
#include <hip/hip_runtime.h>
#include <cstdint>
#include <cstddef>

#define B_ 512
#define S_ 336
#define F_ 16
#define H_ 256
#define P_ 48

typedef __bf16 bhalf;
typedef __attribute__((ext_vector_type(8))) __bf16 bhalf8;
typedef __attribute__((ext_vector_type(4))) float f32x4;

#define MFMA16(A, Bv, C) __builtin_amdgcn_mfma_f32_16x16x32_bf16((A), (Bv), (C), 0, 0, 0)

__device__ __forceinline__ float fastrcp(float x) { return __builtin_amdgcn_rcpf(x); }
__device__ __forceinline__ float sigm(float x) { return fastrcp(1.0f + __expf(-x)); }
__device__ __forceinline__ float tanh_f(float x) { return 2.0f * fastrcp(1.0f + __expf(-2.0f * x)) - 1.0f; }

__device__ __forceinline__ bhalf u16_to_bf(unsigned int u) {
  return __builtin_bit_cast(__bf16, (unsigned short)u);
}
__device__ __forceinline__ unsigned short bf_to_u16(bhalf b) {
  return __builtin_bit_cast(unsigned short, b);
}

__device__ __forceinline__ bhalf8 bzero8() {
  bhalf8 v;
#pragma unroll
  for (int j = 0; j < 8; ++j) v[j] = (bhalf)0.0f;
  return v;
}

// ---------------------------------------------------------------------------
// Encoder: weight-stationary MFMA flag pipeline (structure verified in r6).
// CHANGE vs r6: h-channel is a packed-u32 plane (lo16 = bf16 hi, hi16 = bf16
// lo) accessed with RELAXED AGENT-scope atomics — per-access coherence-point
// ops, NO buffer_wbl2/buffer_inv full-cache maintenance (the measured
// 14.3 us/step cost). Ordering: __syncthreads drains vmcnt before the
// relaxed flag add; consumer loads are themselves scope-marked.
// ---------------------------------------------------------------------------
__global__ __launch_bounds__(128, 1) void enc_kernel(
    const float* __restrict__ Whh, const float* __restrict__ Wih,
    const float* __restrict__ bih, const float* __restrict__ bhh,
    const float* __restrict__ xb,        // [B][S][F] fp32
    bhalf* __restrict__ enc_out,         // [B][S][H]
    float* __restrict__ hcur,            // [B][H] final h, fp32 exact
    unsigned int* __restrict__ hpack,    // [2][B][H] relaxed-atomic channel
    unsigned int* __restrict__ flags)    // [32][S]
{
  __shared__ bhalf lds_lo[54 * 64 * 8];          // lo-plane B-frags, both waves
  const bhalf8* lds_v = (const bhalf8*)lds_lo;

  const int tid  = threadIdx.x;
  const int lane = tid & 63;
  const int wv   = tid >> 6;
  const int ncol = lane & 15;
  const int quad = lane >> 4;

  const int blk = blockIdx.x;
  const int g   = (blk & 7) * 4 + (blk >> 6);   // group 0..31
  const int w   = (blk >> 3) & 7;               // member 0..7
  const int b0  = g * 16;
  const int iw0 = w * 32;
  const int i0  = iw0 + wv * 16;

  // ---- lo-plane B-frags into LDS ----
  for (int it = tid; it < 54 * 64; it += 128) {
    const int fi = it >> 6;
    const int ln = it & 63;
    const int kt = fi % 9;
    const int rem = fi / 9;
    const int gg = rem % 3;
    const int wv2 = rem / 3;
    const int jrow = gg * 256 + iw0 + wv2 * 16 + (ln & 15);
    const int kbase = kt * 32 + ((ln >> 4) << 3);
    bhalf* dst = lds_lo + (size_t)it * 8;
#pragma unroll
    for (int j = 0; j < 8; ++j) {
      const int k = kbase + j;
      float v = 0.0f;
      if (k < 256) v = Whh[(size_t)jrow * 256 + k];
      else if (k < 272) v = Wih[(size_t)jrow * 16 + (k - 256)];
      const bhalf hi = (bhalf)v;
      dst[j] = (bhalf)(v - (float)hi);
    }
  }

  // ---- hi-plane B-frags in registers ----
  bhalf8 bWh[3][9];
#pragma unroll
  for (int gg = 0; gg < 3; ++gg) {
    const int jrow = gg * 256 + i0 + ncol;
#pragma unroll
    for (int kt = 0; kt < 9; ++kt) {
      bhalf8 v = bzero8();
      if (kt < 8) {
        const float* src = Whh + (size_t)jrow * 256 + kt * 32 + quad * 8;
#pragma unroll
        for (int j = 0; j < 8; ++j) v[j] = (bhalf)src[j];
      } else if (quad < 2) {
        const float* src = Wih + (size_t)jrow * 16 + quad * 8;
#pragma unroll
        for (int j = 0; j < 8; ++j) v[j] = (bhalf)src[j];
      }
      bWh[gg][kt] = v;
    }
  }

  const int jr = i0 + ncol;
  const float bR  = bih[jr]       + bhh[jr];
  const float bZ  = bih[256 + jr] + bhh[256 + jr];
  const float bNx = bih[512 + jr];
  const float bNh = bhh[512 + jr];

  __syncthreads();

  const int bA = b0 + ncol;
  const int kA = quad * 8;

  float hold[4] = {0.0f, 0.0f, 0.0f, 0.0f};

  for (int t = 0; t < S_; ++t) {
    if (t > 0) {
      unsigned int* fp = &flags[g * S_ + (t - 1)];
      if (tid == 0) {
        while (__hip_atomic_load(fp, __ATOMIC_RELAXED, __HIP_MEMORY_SCOPE_AGENT) < 8u)
          __builtin_amdgcn_s_sleep(1);
      }
      __syncthreads();
    }

    // x hi/lo A-frags (fp32 source, split on the fly)
    bhalf8 xh = bzero8(), xl = bzero8();
    if (quad < 2) {
      const float* xp = xb + ((size_t)bA * S_ + t) * F_ + quad * 8;
#pragma unroll
      for (int j = 0; j < 8; ++j) {
        const float v = xp[j];
        const bhalf h = (bhalf)v;
        xh[j] = h;
        xl[j] = (bhalf)(v - (float)h);
      }
    }

    f32x4 aR0 = {0,0,0,0}, aR1 = {0,0,0,0}, aR2 = {0,0,0,0};
    f32x4 aZ0 = {0,0,0,0}, aZ1 = {0,0,0,0}, aZ2 = {0,0,0,0};
    f32x4 aN0 = {0,0,0,0}, aN1 = {0,0,0,0}, aN2 = {0,0,0,0};
    f32x4 aNx = {0,0,0,0};

    if (t > 0) {
      const int slot = (t - 1) & 1;
      const unsigned int* hp = hpack + ((size_t)slot * B_ + bA) * H_ + kA;
#pragma unroll
      for (int kt = 0; kt < 8; ++kt) {
        bhalf8 Ah, Al;
#pragma unroll
        for (int j = 0; j < 8; ++j) {
          const unsigned int wrd = __hip_atomic_load(hp + kt * 32 + j,
                                                     __ATOMIC_RELAXED,
                                                     __HIP_MEMORY_SCOPE_AGENT);
          Ah[j] = u16_to_bf(wrd);
          Al[j] = u16_to_bf(wrd >> 16);
        }
        const bhalf8 wl0 = lds_v[((wv * 3 + 0) * 9 + kt) * 64 + lane];
        const bhalf8 wl1 = lds_v[((wv * 3 + 1) * 9 + kt) * 64 + lane];
        const bhalf8 wl2 = lds_v[((wv * 3 + 2) * 9 + kt) * 64 + lane];
        aR0 = MFMA16(Ah, bWh[0][kt], aR0);
        aR1 = MFMA16(Ah, wl0, aR1);
        aR2 = MFMA16(Al, bWh[0][kt], aR2);
        aZ0 = MFMA16(Ah, bWh[1][kt], aZ0);
        aZ1 = MFMA16(Ah, wl1, aZ1);
        aZ2 = MFMA16(Al, bWh[1][kt], aZ2);
        aN0 = MFMA16(Ah, bWh[2][kt], aN0);
        aN1 = MFMA16(Ah, wl2, aN1);
        aN2 = MFMA16(Al, bWh[2][kt], aN2);
      }
    }
    {  // kt = 8: x-part (R/Z join gate accs; N x-part separate)
      const bhalf8 wl0 = lds_v[((wv * 3 + 0) * 9 + 8) * 64 + lane];
      const bhalf8 wl1 = lds_v[((wv * 3 + 1) * 9 + 8) * 64 + lane];
      const bhalf8 wl2 = lds_v[((wv * 3 + 2) * 9 + 8) * 64 + lane];
      aR0 = MFMA16(xh, bWh[0][8], aR0);
      aR1 = MFMA16(xh, wl0, aR1);
      aR2 = MFMA16(xl, bWh[0][8], aR2);
      aZ0 = MFMA16(xh, bWh[1][8], aZ0);
      aZ1 = MFMA16(xh, wl1, aZ1);
      aZ2 = MFMA16(xl, bWh[1][8], aZ2);
      aNx = MFMA16(xh, bWh[2][8], aNx);
      aNx = MFMA16(xh, wl2, aNx);
      aNx = MFMA16(xl, bWh[2][8], aNx);
    }

    // ---- gates + publish (C/D: col = lane&15, row = quad*4 + reg) ----
    const int iL = i0 + ncol;
#pragma unroll
    for (int r = 0; r < 4; ++r) {
      const int bb = b0 + quad * 4 + r;
      const float sR  = aR0[r] + aR1[r] + aR2[r] + bR;
      const float sZ  = aZ0[r] + aZ1[r] + aZ2[r] + bZ;
      const float nhv = aN0[r] + aN1[r] + aN2[r] + bNh;
      const float nxv = aNx[r] + bNx;
      const float rr = sigm(sR);
      const float zz = sigm(sZ);
      const float nn = tanh_f(nxv + rr * nhv);
      const float h2 = (1.0f - zz) * nn + zz * hold[r];
      hold[r] = h2;
      const bhalf hi = (bhalf)h2;
      const bhalf lo = (bhalf)(h2 - (float)hi);
      enc_out[((size_t)bb * S_ + t) * H_ + iL] = hi;
      const unsigned int wrd =
          (unsigned int)bf_to_u16(hi) | ((unsigned int)bf_to_u16(lo) << 16);
      __hip_atomic_store(&hpack[((size_t)(t & 1) * B_ + bb) * H_ + iL], wrd,
                         __ATOMIC_RELAXED, __HIP_MEMORY_SCOPE_AGENT);
    }

    __syncthreads();   // drains vmcnt(0): channel stores complete before flag
    if (tid == 0) {
      __hip_atomic_fetch_add(&flags[g * S_ + t], 1u, __ATOMIC_RELAXED,
                             __HIP_MEMORY_SCOPE_AGENT);
    }
  }

#pragma unroll
  for (int r = 0; r < 4; ++r)
    hcur[(size_t)(b0 + quad * 4 + r) * H_ + i0 + ncol] = hold[r];
}

// ---------------------------------------------------------------------------
// Prep: dec GRU weights -> bf16 pack wb[768][512] ([0:256]=Whh row, [256:512]=Wih row)
// ---------------------------------------------------------------------------
__global__ __launch_bounds__(256) void wpack_kernel(const float* __restrict__ Whh,
                                                    const float* __restrict__ Wih,
                                                    bhalf* __restrict__ wb) {
  const int idx = blockIdx.x * 256 + threadIdx.x;
  if (idx >= 768 * 512) return;
  const int row = idx >> 9, c = idx & 511;
  const float v = (c < 256) ? Whh[(size_t)row * 256 + c]
                            : Wih[(size_t)row * 256 + (c - 256)];
  wb[idx] = (bhalf)v;
}

// ---------------------------------------------------------------------------
// Prep: attW -> bf16 pack ab[336][288] ([0:272]=attW row, [272:288]=0)
// ---------------------------------------------------------------------------
__global__ __launch_bounds__(256) void apack_kernel(const float* __restrict__ attW,
                                                    bhalf* __restrict__ ab) {
  const int idx = blockIdx.x * 256 + threadIdx.x;
  if (idx >= 336 * 288) return;
  const int row = idx / 288, c = idx - row * 288;
  ab[idx] = (c < 272) ? (bhalf)attW[(size_t)row * 272 + c] : (bhalf)0.0f;
}

// ---------------------------------------------------------------------------
// Decoder: ONE fused kernel, all 48 steps. 256 blocks x 512 threads (8 waves,
// 1 block/CU). Block owns 2 batch rows. GRU is K-split: half-threads (hf=0)
// do the h x Whh part, hf=1 the c x Wih part (N-gate's nh/nx split is natural).
// GRU + attention weights are bf16 (prep-packed, halves L2 traffic); all
// accumulation fp32 with 4-way chain splitting.
// ---------------------------------------------------------------------------
__global__ __launch_bounds__(512) void dec_kernel(
    const bhalf* __restrict__ wb,       // [768][512]
    const bhalf* __restrict__ ab,       // [336][288]
    const float* __restrict__ attb,
    const float* __restrict__ bih, const float* __restrict__ bhh,
    const float* __restrict__ outW, const float* __restrict__ outb,
    const float* __restrict__ linW, const float* __restrict__ linb,
    const bhalf* __restrict__ enc_out, const float* __restrict__ hcur,
    const float* __restrict__ xb, float* __restrict__ dout)
{
  __shared__ float hyL[2][288];     // [h(256) | y(16) | 0-pad(16)]
  __shared__ float cL[2][260];
  __shared__ float sc[2][S_];
  __shared__ float pR[2][2][256];   // [hf][r][jj]
  __shared__ float pZ[2][2][256];
  __shared__ float pN[2][2][256];
  __shared__ float oL[2][16];
  const int tid  = threadIdx.x;
  const int lane = tid & 63;
  const int wv   = tid >> 6;
  const int b0   = blockIdx.x * 2;
  const int jj   = tid & 255;
  const int hf   = tid >> 8;

  for (int e = tid; e < 2 * 256; e += 512)
    hyL[e >> 8][e & 255] = hcur[(size_t)(b0 + (e >> 8)) * H_ + (e & 255)];
  if (tid < 32)
    hyL[tid >> 4][256 + (tid & 15)] =
        xb[((size_t)(b0 + (tid >> 4)) * S_ + (S_ - 1)) * F_ + (tid & 15)];
  else if (tid < 64)
    hyL[(tid - 32) >> 4][272 + (tid & 15)] = 0.0f;

  // biases for gate combine (used by tid<256)
  const float bRv  = bih[jj]       + bhh[jj];
  const float bZv  = bih[256 + jj] + bhh[256 + jj];
  const float bNxv = bih[512 + jj];
  const float bNhv = bhh[512 + jj];

  // GRU weight rows for this (jj, hf)
  const bhalf* w0 = wb + (size_t)jj * 512 + hf * 256;          // R
  const bhalf* w1 = wb + (size_t)(256 + jj) * 512 + hf * 256;  // Z
  const bhalf* w2 = wb + (size_t)(512 + jj) * 512 + hf * 256;  // N
  __syncthreads();

  for (int p = 0; p < P_; ++p) {
    // ---- attention scores (bf16 weights, fp32 acc, 4-way chains) ----
    for (int e = tid; e < 2 * S_; e += 512) {
      const int r = (e >= S_) ? 1 : 0;
      const int s = e - r * S_;
      const bhalf* wr = ab + (size_t)s * 288;
      const float* hv = hyL[r];
      float d0 = 0, d1 = 0, d2 = 0, d3 = 0;
#pragma unroll 4
      for (int k8 = 0; k8 < 36; ++k8) {
        const bhalf8 q = *(const bhalf8*)(wr + k8 * 8);
        const float* v = hv + k8 * 8;
        d0 += (float)q[0] * v[0] + (float)q[4] * v[4];
        d1 += (float)q[1] * v[1] + (float)q[5] * v[5];
        d2 += (float)q[2] * v[2] + (float)q[6] * v[6];
        d3 += (float)q[3] * v[3] + (float)q[7] * v[7];
      }
      sc[r][s] = d0 + d1 + d2 + d3 + attb[s];
    }
    __syncthreads();

    // ---- softmax: wave r handles row r ----
    if (wv < 2) {
      const int r = wv;
      float mx = -3e38f;
      for (int s = lane; s < S_; s += 64) mx = fmaxf(mx, sc[r][s]);
#pragma unroll
      for (int o = 32; o > 0; o >>= 1) mx = fmaxf(mx, __shfl_xor(mx, o, 64));
      float sum = 0.0f;
      for (int s = lane; s < S_; s += 64) {
        const float e = expf(sc[r][s] - mx);
        sc[r][s] = e;
        sum += e;
      }
#pragma unroll
      for (int o = 32; o > 0; o >>= 1) sum += __shfl_xor(sum, o, 64);
      const float inv = 1.0f / sum;
      for (int s = lane; s < S_; s += 64) sc[r][s] *= inv;
    }
    __syncthreads();

    // ---- combine: thread (hf=r, jj=i) ----
    {
      const int r = hf, i = jj;
      const bhalf* ep = enc_out + (size_t)(b0 + r) * S_ * H_ + i;
      float a0 = 0, a1 = 0, a2 = 0, a3 = 0;
      for (int s = 0; s < S_; s += 4) {
        a0 += sc[r][s]     * (float)ep[(size_t)(s)     * H_];
        a1 += sc[r][s + 1] * (float)ep[(size_t)(s + 1) * H_];
        a2 += sc[r][s + 2] * (float)ep[(size_t)(s + 2) * H_];
        a3 += sc[r][s + 3] * (float)ep[(size_t)(s + 3) * H_];
      }
      cL[r][i] = a0 + a1 + a2 + a3;
    }
    __syncthreads();

    // ---- GRU dots, K-split: hf=0 -> h x Whh, hf=1 -> c x Wih ----
    {
      const float* v0 = hf ? cL[0] : hyL[0];
      const float* v1 = hf ? cL[1] : hyL[1];
      float accR[2] = {0, 0}, accZ[2] = {0, 0}, accN[2] = {0, 0};
#pragma unroll 2
      for (int k8 = 0; k8 < 32; ++k8) {
        const bhalf8 qR = *(const bhalf8*)(w0 + k8 * 8);
        const bhalf8 qZ = *(const bhalf8*)(w1 + k8 * 8);
        const bhalf8 qN = *(const bhalf8*)(w2 + k8 * 8);
#pragma unroll
        for (int r = 0; r < 2; ++r) {
          const float* v = (r ? v1 : v0) + k8 * 8;
          float sR = 0, sZ = 0, sN = 0;
#pragma unroll
          for (int j = 0; j < 8; ++j) {
            sR += (float)qR[j] * v[j];
            sZ += (float)qZ[j] * v[j];
            sN += (float)qN[j] * v[j];
          }
          accR[r] += sR; accZ[r] += sZ; accN[r] += sN;
        }
      }
#pragma unroll
      for (int r = 0; r < 2; ++r) {
        pR[hf][r][jj] = accR[r];
        pZ[hf][r][jj] = accZ[r];
        pN[hf][r][jj] = accN[r];
      }
    }
    __syncthreads();

    // ---- gate combine + h update (tid<256) ----
    if (tid < 256) {
#pragma unroll
      for (int r = 0; r < 2; ++r) {
        const float sR = pR[0][r][jj] + pR[1][r][jj] + bRv;
        const float sZ = pZ[0][r][jj] + pZ[1][r][jj] + bZv;
        const float nh = pN[0][r][jj] + bNhv;
        const float nx = pN[1][r][jj] + bNxv;
        const float rr = 1.0f / (1.0f + expf(-sR));
        const float zz = 1.0f / (1.0f + expf(-sZ));
        const float nn = tanhf(nx + rr * nh);
        hyL[r][jj] = (1.0f - zz) * nn + zz * hyL[r][jj];
      }
    }
    __syncthreads();

    // ---- out = h2 @ outW.T + outb; y feedback in place ----
    if (tid < 32) {
      const int r = tid >> 4, f = tid & 15;
      const float* wr = outW + (size_t)f * H_;
      const float* hv = hyL[r];
      float a0 = 0, a1 = 0, a2 = 0, a3 = 0;
      for (int k = 0; k < H_; k += 4) {
        a0 += wr[k]     * hv[k];
        a1 += wr[k + 1] * hv[k + 1];
        a2 += wr[k + 2] * hv[k + 2];
        a3 += wr[k + 3] * hv[k + 3];
      }
      const float o = a0 + a1 + a2 + a3 + outb[f];
      oL[r][f] = o;
      hyL[r][256 + f] = o;
    }
    __syncthreads();

    // ---- pred ----
    if (tid < 2) {
      float pr = linb[0];
#pragma unroll
      for (int f = 0; f < 16; ++f) pr += oL[tid][f] * linW[f];
      dout[(size_t)(b0 + tid) * P_ + p] = pr;
    }
    __syncthreads();
  }
}

// ---------------------------------------------------------------------------
extern "C" void kernel_launch(void* const* d_in, const int* in_sizes, int n_in,
                              void* d_out, int out_size, void* d_ws, size_t ws_size,
                              hipStream_t stream)
{
  (void)in_sizes; (void)n_in; (void)out_size;
  const float* xb      = (const float*)d_in[0];
  const float* enc_Wih = (const float*)d_in[1];
  const float* enc_Whh = (const float*)d_in[2];
  const float* enc_bih = (const float*)d_in[3];
  const float* enc_bhh = (const float*)d_in[4];
  const float* att_W   = (const float*)d_in[5];
  const float* att_b   = (const float*)d_in[6];
  const float* dec_Wih = (const float*)d_in[7];
  const float* dec_Whh = (const float*)d_in[8];
  const float* dec_bih = (const float*)d_in[9];
  const float* dec_bhh = (const float*)d_in[10];
  const float* out_W   = (const float*)d_in[11];
  const float* out_b   = (const float*)d_in[12];
  const float* lin_W   = (const float*)d_in[13];
  const float* lin_b   = (const float*)d_in[14];
  float* dout = (float*)d_out;

  char* ws = (char*)d_ws;
  const size_t off_enc = 0;                                     // bf16 enc_out
  const size_t off_hp  = off_enc + (size_t)B_ * S_ * H_ * 2;    // 88,080,384
  const size_t off_hc  = off_hp + (size_t)2 * B_ * H_ * 4;      // hpack u32
  const size_t off_wb  = off_hc + (size_t)B_ * H_ * 4;
  const size_t off_ab  = off_wb + (size_t)768 * 512 * 2;
  const size_t off_fl  = off_ab + (size_t)336 * 288 * 2;
  const size_t need    = off_fl + 32 * S_ * sizeof(unsigned int);
  if (ws_size < need) return;

  bhalf* enc_out      = (bhalf*)(ws + off_enc);
  unsigned int* hpack = (unsigned int*)(ws + off_hp);
  float* hcur         = (float*)(ws + off_hc);
  bhalf* wb           = (bhalf*)(ws + off_wb);
  bhalf* ab           = (bhalf*)(ws + off_ab);
  unsigned int* flags = (unsigned int*)(ws + off_fl);

  (void)hipMemsetAsync(flags, 0, 32 * S_ * sizeof(unsigned int), stream);
  wpack_kernel<<<(768 * 512 + 255) / 256, 256, 0, stream>>>(dec_Whh, dec_Wih, wb);
  apack_kernel<<<(336 * 288 + 255) / 256, 256, 0, stream>>>(att_W, ab);
  enc_kernel<<<256, 128, 0, stream>>>(enc_Whh, enc_Wih, enc_bih, enc_bhh, xb,
                                      enc_out, hcur, hpack, flags);
  dec_kernel<<<B_ / 2, 512, 0, stream>>>(wb, ab, att_b, dec_bih, dec_bhh,
                                         out_W, out_b, lin_W, lin_b,
                                         enc_out, hcur, xb, dout);
}

// Round 8
// 5164.419 us; speedup vs baseline: 2.7422x; 1.0638x over previous
//
#include <hip/hip_runtime.h>
#include <cstdint>
#include <cstddef>

#define B_ 512
#define S_ 336
#define F_ 16
#define H_ 256
#define P_ 48

typedef __bf16 bhalf;
typedef __attribute__((ext_vector_type(8))) __bf16 bhalf8;
typedef __attribute__((ext_vector_type(4))) float f32x4;

#define MFMA16(A, Bv, C) __builtin_amdgcn_mfma_f32_16x16x32_bf16((A), (Bv), (C), 0, 0, 0)

__device__ __forceinline__ float fastrcp(float x) { return __builtin_amdgcn_rcpf(x); }
__device__ __forceinline__ float sigm(float x) { return fastrcp(1.0f + __expf(-x)); }
__device__ __forceinline__ float tanh_f(float x) { return 2.0f * fastrcp(1.0f + __expf(-2.0f * x)) - 1.0f; }

__device__ __forceinline__ bhalf u16_to_bf(unsigned int u) {
  return __builtin_bit_cast(__bf16, (unsigned short)u);
}
__device__ __forceinline__ unsigned short bf_to_u16(bhalf b) {
  return __builtin_bit_cast(unsigned short, b);
}

__device__ __forceinline__ bhalf8 bzero8() {
  bhalf8 v;
#pragma unroll
  for (int j = 0; j < 8; ++j) v[j] = (bhalf)0.0f;
  return v;
}

// ---------------------------------------------------------------------------
// Encoder: weight-stationary MFMA flag pipeline (structure verified r6/r7).
// CHANGE vs r7: h-channel A-frag loads are u64 relaxed AGENT-scope atomics
// (32 ops/lane instead of 64) — same coherence-point semantics, half the
// issue slots on the step-critical load path.
// ---------------------------------------------------------------------------
__global__ __launch_bounds__(128, 1) void enc_kernel(
    const float* __restrict__ Whh, const float* __restrict__ Wih,
    const float* __restrict__ bih, const float* __restrict__ bhh,
    const float* __restrict__ xb,        // [B][S][F] fp32
    bhalf* __restrict__ enc_out,         // [B][S][H]
    float* __restrict__ hcur,            // [B][H] final h, fp32 exact
    unsigned int* __restrict__ hpack,    // [2][B][H] relaxed-atomic channel
    unsigned int* __restrict__ flags)    // [32][S]
{
  __shared__ bhalf lds_lo[54 * 64 * 8];          // lo-plane B-frags, both waves
  const bhalf8* lds_v = (const bhalf8*)lds_lo;

  const int tid  = threadIdx.x;
  const int lane = tid & 63;
  const int wv   = tid >> 6;
  const int ncol = lane & 15;
  const int quad = lane >> 4;

  const int blk = blockIdx.x;
  const int g   = (blk & 7) * 4 + (blk >> 6);   // group 0..31
  const int w   = (blk >> 3) & 7;               // member 0..7
  const int b0  = g * 16;
  const int iw0 = w * 32;
  const int i0  = iw0 + wv * 16;

  // ---- lo-plane B-frags into LDS ----
  for (int it = tid; it < 54 * 64; it += 128) {
    const int fi = it >> 6;
    const int ln = it & 63;
    const int kt = fi % 9;
    const int rem = fi / 9;
    const int gg = rem % 3;
    const int wv2 = rem / 3;
    const int jrow = gg * 256 + iw0 + wv2 * 16 + (ln & 15);
    const int kbase = kt * 32 + ((ln >> 4) << 3);
    bhalf* dst = lds_lo + (size_t)it * 8;
#pragma unroll
    for (int j = 0; j < 8; ++j) {
      const int k = kbase + j;
      float v = 0.0f;
      if (k < 256) v = Whh[(size_t)jrow * 256 + k];
      else if (k < 272) v = Wih[(size_t)jrow * 16 + (k - 256)];
      const bhalf hi = (bhalf)v;
      dst[j] = (bhalf)(v - (float)hi);
    }
  }

  // ---- hi-plane B-frags in registers ----
  bhalf8 bWh[3][9];
#pragma unroll
  for (int gg = 0; gg < 3; ++gg) {
    const int jrow = gg * 256 + i0 + ncol;
#pragma unroll
    for (int kt = 0; kt < 9; ++kt) {
      bhalf8 v = bzero8();
      if (kt < 8) {
        const float* src = Whh + (size_t)jrow * 256 + kt * 32 + quad * 8;
#pragma unroll
        for (int j = 0; j < 8; ++j) v[j] = (bhalf)src[j];
      } else if (quad < 2) {
        const float* src = Wih + (size_t)jrow * 16 + quad * 8;
#pragma unroll
        for (int j = 0; j < 8; ++j) v[j] = (bhalf)src[j];
      }
      bWh[gg][kt] = v;
    }
  }

  const int jr = i0 + ncol;
  const float bR  = bih[jr]       + bhh[jr];
  const float bZ  = bih[256 + jr] + bhh[256 + jr];
  const float bNx = bih[512 + jr];
  const float bNh = bhh[512 + jr];

  __syncthreads();

  const int bA = b0 + ncol;
  const int kA = quad * 8;

  float hold[4] = {0.0f, 0.0f, 0.0f, 0.0f};

  for (int t = 0; t < S_; ++t) {
    if (t > 0) {
      unsigned int* fp = &flags[g * S_ + (t - 1)];
      if (tid == 0) {
        while (__hip_atomic_load(fp, __ATOMIC_RELAXED, __HIP_MEMORY_SCOPE_AGENT) < 8u)
          __builtin_amdgcn_s_sleep(1);
      }
      __syncthreads();
    }

    // x hi/lo A-frags (fp32 source, split on the fly)
    bhalf8 xh = bzero8(), xl = bzero8();
    if (quad < 2) {
      const float* xp = xb + ((size_t)bA * S_ + t) * F_ + quad * 8;
#pragma unroll
      for (int j = 0; j < 8; ++j) {
        const float v = xp[j];
        const bhalf h = (bhalf)v;
        xh[j] = h;
        xl[j] = (bhalf)(v - (float)h);
      }
    }

    f32x4 aR0 = {0,0,0,0}, aR1 = {0,0,0,0}, aR2 = {0,0,0,0};
    f32x4 aZ0 = {0,0,0,0}, aZ1 = {0,0,0,0}, aZ2 = {0,0,0,0};
    f32x4 aN0 = {0,0,0,0}, aN1 = {0,0,0,0}, aN2 = {0,0,0,0};
    f32x4 aNx = {0,0,0,0};

    if (t > 0) {
      const int slot = (t - 1) & 1;
      const unsigned long long* hp64 =
          (const unsigned long long*)(hpack + ((size_t)slot * B_ + bA) * H_ + kA);
#pragma unroll
      for (int kt = 0; kt < 8; ++kt) {
        bhalf8 Ah, Al;
#pragma unroll
        for (int j2 = 0; j2 < 4; ++j2) {
          const unsigned long long w2 =
              __hip_atomic_load(hp64 + kt * 16 + j2, __ATOMIC_RELAXED,
                                __HIP_MEMORY_SCOPE_AGENT);
          Ah[2 * j2]     = u16_to_bf((unsigned int)w2);
          Al[2 * j2]     = u16_to_bf((unsigned int)(w2 >> 16));
          Ah[2 * j2 + 1] = u16_to_bf((unsigned int)(w2 >> 32));
          Al[2 * j2 + 1] = u16_to_bf((unsigned int)(w2 >> 48));
        }
        const bhalf8 wl0 = lds_v[((wv * 3 + 0) * 9 + kt) * 64 + lane];
        const bhalf8 wl1 = lds_v[((wv * 3 + 1) * 9 + kt) * 64 + lane];
        const bhalf8 wl2 = lds_v[((wv * 3 + 2) * 9 + kt) * 64 + lane];
        aR0 = MFMA16(Ah, bWh[0][kt], aR0);
        aR1 = MFMA16(Ah, wl0, aR1);
        aR2 = MFMA16(Al, bWh[0][kt], aR2);
        aZ0 = MFMA16(Ah, bWh[1][kt], aZ0);
        aZ1 = MFMA16(Ah, wl1, aZ1);
        aZ2 = MFMA16(Al, bWh[1][kt], aZ2);
        aN0 = MFMA16(Ah, bWh[2][kt], aN0);
        aN1 = MFMA16(Ah, wl2, aN1);
        aN2 = MFMA16(Al, bWh[2][kt], aN2);
      }
    }
    {  // kt = 8: x-part (R/Z join gate accs; N x-part separate)
      const bhalf8 wl0 = lds_v[((wv * 3 + 0) * 9 + 8) * 64 + lane];
      const bhalf8 wl1 = lds_v[((wv * 3 + 1) * 9 + 8) * 64 + lane];
      const bhalf8 wl2 = lds_v[((wv * 3 + 2) * 9 + 8) * 64 + lane];
      aR0 = MFMA16(xh, bWh[0][8], aR0);
      aR1 = MFMA16(xh, wl0, aR1);
      aR2 = MFMA16(xl, bWh[0][8], aR2);
      aZ0 = MFMA16(xh, bWh[1][8], aZ0);
      aZ1 = MFMA16(xh, wl1, aZ1);
      aZ2 = MFMA16(xl, bWh[1][8], aZ2);
      aNx = MFMA16(xh, bWh[2][8], aNx);
      aNx = MFMA16(xh, wl2, aNx);
      aNx = MFMA16(xl, bWh[2][8], aNx);
    }

    // ---- gates + publish (C/D: col = lane&15, row = quad*4 + reg) ----
    const int iL = i0 + ncol;
#pragma unroll
    for (int r = 0; r < 4; ++r) {
      const int bb = b0 + quad * 4 + r;
      const float sR  = aR0[r] + aR1[r] + aR2[r] + bR;
      const float sZ  = aZ0[r] + aZ1[r] + aZ2[r] + bZ;
      const float nhv = aN0[r] + aN1[r] + aN2[r] + bNh;
      const float nxv = aNx[r] + bNx;
      const float rr = sigm(sR);
      const float zz = sigm(sZ);
      const float nn = tanh_f(nxv + rr * nhv);
      const float h2 = (1.0f - zz) * nn + zz * hold[r];
      hold[r] = h2;
      const bhalf hi = (bhalf)h2;
      const bhalf lo = (bhalf)(h2 - (float)hi);
      enc_out[((size_t)bb * S_ + t) * H_ + iL] = hi;
      const unsigned int wrd =
          (unsigned int)bf_to_u16(hi) | ((unsigned int)bf_to_u16(lo) << 16);
      __hip_atomic_store(&hpack[((size_t)(t & 1) * B_ + bb) * H_ + iL], wrd,
                         __ATOMIC_RELAXED, __HIP_MEMORY_SCOPE_AGENT);
    }

    __syncthreads();   // drains vmcnt(0): channel stores complete before flag
    if (tid == 0) {
      __hip_atomic_fetch_add(&flags[g * S_ + t], 1u, __ATOMIC_RELAXED,
                             __HIP_MEMORY_SCOPE_AGENT);
    }
  }

#pragma unroll
  for (int r = 0; r < 4; ++r)
    hcur[(size_t)(b0 + quad * 4 + r) * H_ + i0 + ncol] = hold[r];
}

// ---------------------------------------------------------------------------
// Prep: dec GRU weights -> bf16 pack wb[768][512] ([0:256]=Whh, [256:512]=Wih)
// ---------------------------------------------------------------------------
__global__ __launch_bounds__(256) void wpack_kernel(const float* __restrict__ Whh,
                                                    const float* __restrict__ Wih,
                                                    bhalf* __restrict__ wb) {
  const int idx = blockIdx.x * 256 + threadIdx.x;
  if (idx >= 768 * 512) return;
  const int row = idx >> 9, c = idx & 511;
  const float v = (c < 256) ? Whh[(size_t)row * 256 + c]
                            : Wih[(size_t)row * 256 + (c - 256)];
  wb[idx] = (bhalf)v;
}

// ---------------------------------------------------------------------------
// Prep: attW -> bf16 TRANSPOSED pack abT[36][336][8]:
// abT[k8][s][j] = attW[s][k8*8+j] (0 for k >= 272). Coalesced score loads.
// ---------------------------------------------------------------------------
__global__ __launch_bounds__(256) void apack_kernel(const float* __restrict__ attW,
                                                    bhalf* __restrict__ abT) {
  const int idx = blockIdx.x * 256 + threadIdx.x;
  if (idx >= 36 * 336 * 8) return;
  const int j = idx & 7;
  const int s = (idx >> 3) % 336;
  const int k8 = idx / (8 * 336);
  const int k = k8 * 8 + j;
  abT[idx] = (k < 272) ? (bhalf)attW[(size_t)s * 272 + k] : (bhalf)0.0f;
}

// ---------------------------------------------------------------------------
// Decoder: ONE fused kernel, all 48 steps. 256 blocks x 512 threads.
// Block owns 2 batch rows. CHANGE vs r7: combine phase re-mapped to
// (row, s-chunk of 42, col-group of 8) with bhalf8 16-B loads (42 loads/thread
// instead of 336 scalar ushort loads) + LDS partial reduction; attention
// score weights transposed for lane-coalesced loads.
// ---------------------------------------------------------------------------
__global__ __launch_bounds__(512) void dec_kernel(
    const bhalf* __restrict__ wb,       // [768][512]
    const bhalf* __restrict__ abT,      // [36][336][8]
    const float* __restrict__ attb,
    const float* __restrict__ bih, const float* __restrict__ bhh,
    const float* __restrict__ outW, const float* __restrict__ outb,
    const float* __restrict__ linW, const float* __restrict__ linb,
    const bhalf* __restrict__ enc_out, const float* __restrict__ hcur,
    const float* __restrict__ xb, float* __restrict__ dout)
{
  __shared__ float hyL[2][288];     // [h(256) | y(16) | 0-pad(16)]
  __shared__ float cL[2][260];
  __shared__ float sc[2][S_];
  __shared__ float pC[8][2][32][8]; // combine partials [s-chunk][r][g][j]
  __shared__ float pR[2][2][256];   // [hf][r][jj]
  __shared__ float pZ[2][2][256];
  __shared__ float pN[2][2][256];
  __shared__ float oL[2][16];
  const int tid  = threadIdx.x;
  const int lane = tid & 63;
  const int wv   = tid >> 6;
  const int b0   = blockIdx.x * 2;
  const int jj   = tid & 255;
  const int hf   = tid >> 8;
  // combine decomposition
  const int cg = tid & 31;          // col-group (8 cols)
  const int ck = (tid >> 5) & 7;    // s-chunk (42 s-values)
  const int cr = tid >> 8;          // row

  for (int e = tid; e < 2 * 256; e += 512)
    hyL[e >> 8][e & 255] = hcur[(size_t)(b0 + (e >> 8)) * H_ + (e & 255)];
  if (tid < 32)
    hyL[tid >> 4][256 + (tid & 15)] =
        xb[((size_t)(b0 + (tid >> 4)) * S_ + (S_ - 1)) * F_ + (tid & 15)];
  else if (tid < 64)
    hyL[(tid - 32) >> 4][272 + (tid & 15)] = 0.0f;

  const float bRv  = bih[jj]       + bhh[jj];
  const float bZv  = bih[256 + jj] + bhh[256 + jj];
  const float bNxv = bih[512 + jj];
  const float bNhv = bhh[512 + jj];

  const bhalf* w0 = wb + (size_t)jj * 512 + hf * 256;          // R
  const bhalf* w1 = wb + (size_t)(256 + jj) * 512 + hf * 256;  // Z
  const bhalf* w2 = wb + (size_t)(512 + jj) * 512 + hf * 256;  // N
  const bhalf* epC = enc_out + ((size_t)(b0 + cr) * S_ + ck * 42) * H_ + cg * 8;
  __syncthreads();

  for (int p = 0; p < P_; ++p) {
    // ---- attention scores (transposed bf16 weights, coalesced) ----
    for (int e = tid; e < 2 * S_; e += 512) {
      const int r = (e >= S_) ? 1 : 0;
      const int s = e - r * S_;
      const float* hv = hyL[r];
      float d0 = 0, d1 = 0, d2 = 0, d3 = 0;
#pragma unroll 4
      for (int k8 = 0; k8 < 36; ++k8) {
        const bhalf8 q = *(const bhalf8*)(abT + ((size_t)k8 * S_ + s) * 8);
        const float* v = hv + k8 * 8;
        d0 += (float)q[0] * v[0] + (float)q[4] * v[4];
        d1 += (float)q[1] * v[1] + (float)q[5] * v[5];
        d2 += (float)q[2] * v[2] + (float)q[6] * v[6];
        d3 += (float)q[3] * v[3] + (float)q[7] * v[7];
      }
      sc[r][s] = d0 + d1 + d2 + d3 + attb[s];
    }
    __syncthreads();

    // ---- softmax: wave r handles row r ----
    if (wv < 2) {
      const int r = wv;
      float mx = -3e38f;
      for (int s = lane; s < S_; s += 64) mx = fmaxf(mx, sc[r][s]);
#pragma unroll
      for (int o = 32; o > 0; o >>= 1) mx = fmaxf(mx, __shfl_xor(mx, o, 64));
      float sum = 0.0f;
      for (int s = lane; s < S_; s += 64) {
        const float e = expf(sc[r][s] - mx);
        sc[r][s] = e;
        sum += e;
      }
#pragma unroll
      for (int o = 32; o > 0; o >>= 1) sum += __shfl_xor(sum, o, 64);
      const float inv = 1.0f / sum;
      for (int s = lane; s < S_; s += 64) sc[r][s] *= inv;
    }
    __syncthreads();

    // ---- combine, vectorized: thread (cr, ck, cg) ----
    {
      float a0 = 0, a1 = 0, a2 = 0, a3 = 0, a4 = 0, a5 = 0, a6 = 0, a7 = 0;
      const float* scrow = sc[cr] + ck * 42;
#pragma unroll 6
      for (int s5 = 0; s5 < 42; ++s5) {
        const bhalf8 v = *(const bhalf8*)(epC + (size_t)s5 * H_);
        const float wgt = scrow[s5];
        a0 += wgt * (float)v[0];
        a1 += wgt * (float)v[1];
        a2 += wgt * (float)v[2];
        a3 += wgt * (float)v[3];
        a4 += wgt * (float)v[4];
        a5 += wgt * (float)v[5];
        a6 += wgt * (float)v[6];
        a7 += wgt * (float)v[7];
      }
      float* pp = pC[ck][cr][cg];
      pp[0] = a0; pp[1] = a1; pp[2] = a2; pp[3] = a3;
      pp[4] = a4; pp[5] = a5; pp[6] = a6; pp[7] = a7;
    }
    __syncthreads();
    {  // reduce 8 partials -> cL[hf][jj]
      const int gg = jj >> 3, j = jj & 7;
      float s = 0.0f;
#pragma unroll
      for (int c = 0; c < 8; ++c) s += pC[c][hf][gg][j];
      cL[hf][jj] = s;
    }
    __syncthreads();

    // ---- GRU dots, K-split: hf=0 -> h x Whh, hf=1 -> c x Wih ----
    {
      const float* v0 = hf ? cL[0] : hyL[0];
      const float* v1 = hf ? cL[1] : hyL[1];
      float accR[2] = {0, 0}, accZ[2] = {0, 0}, accN[2] = {0, 0};
#pragma unroll 2
      for (int k8 = 0; k8 < 32; ++k8) {
        const bhalf8 qR = *(const bhalf8*)(w0 + k8 * 8);
        const bhalf8 qZ = *(const bhalf8*)(w1 + k8 * 8);
        const bhalf8 qN = *(const bhalf8*)(w2 + k8 * 8);
#pragma unroll
        for (int r = 0; r < 2; ++r) {
          const float* v = (r ? v1 : v0) + k8 * 8;
          float sR = 0, sZ = 0, sN = 0;
#pragma unroll
          for (int j = 0; j < 8; ++j) {
            sR += (float)qR[j] * v[j];
            sZ += (float)qZ[j] * v[j];
            sN += (float)qN[j] * v[j];
          }
          accR[r] += sR; accZ[r] += sZ; accN[r] += sN;
        }
      }
#pragma unroll
      for (int r = 0; r < 2; ++r) {
        pR[hf][r][jj] = accR[r];
        pZ[hf][r][jj] = accZ[r];
        pN[hf][r][jj] = accN[r];
      }
    }
    __syncthreads();

    // ---- gate combine + h update (tid<256) ----
    if (tid < 256) {
#pragma unroll
      for (int r = 0; r < 2; ++r) {
        const float sR = pR[0][r][jj] + pR[1][r][jj] + bRv;
        const float sZ = pZ[0][r][jj] + pZ[1][r][jj] + bZv;
        const float nh = pN[0][r][jj] + bNhv;
        const float nx = pN[1][r][jj] + bNxv;
        const float rr = 1.0f / (1.0f + expf(-sR));
        const float zz = 1.0f / (1.0f + expf(-sZ));
        const float nn = tanhf(nx + rr * nh);
        hyL[r][jj] = (1.0f - zz) * nn + zz * hyL[r][jj];
      }
    }
    __syncthreads();

    // ---- out = h2 @ outW.T + outb; y feedback in place ----
    if (tid < 32) {
      const int r = tid >> 4, f = tid & 15;
      const float* wr = outW + (size_t)f * H_;
      const float* hv = hyL[r];
      float a0 = 0, a1 = 0, a2 = 0, a3 = 0;
      for (int k = 0; k < H_; k += 4) {
        a0 += wr[k]     * hv[k];
        a1 += wr[k + 1] * hv[k + 1];
        a2 += wr[k + 2] * hv[k + 2];
        a3 += wr[k + 3] * hv[k + 3];
      }
      const float o = a0 + a1 + a2 + a3 + outb[f];
      oL[r][f] = o;
      hyL[r][256 + f] = o;
    }
    __syncthreads();

    // ---- pred ----
    if (tid < 2) {
      float pr = linb[0];
#pragma unroll
      for (int f = 0; f < 16; ++f) pr += oL[tid][f] * linW[f];
      dout[(size_t)(b0 + tid) * P_ + p] = pr;
    }
    __syncthreads();
  }
}

// ---------------------------------------------------------------------------
extern "C" void kernel_launch(void* const* d_in, const int* in_sizes, int n_in,
                              void* d_out, int out_size, void* d_ws, size_t ws_size,
                              hipStream_t stream)
{
  (void)in_sizes; (void)n_in; (void)out_size;
  const float* xb      = (const float*)d_in[0];
  const float* enc_Wih = (const float*)d_in[1];
  const float* enc_Whh = (const float*)d_in[2];
  const float* enc_bih = (const float*)d_in[3];
  const float* enc_bhh = (const float*)d_in[4];
  const float* att_W   = (const float*)d_in[5];
  const float* att_b   = (const float*)d_in[6];
  const float* dec_Wih = (const float*)d_in[7];
  const float* dec_Whh = (const float*)d_in[8];
  const float* dec_bih = (const float*)d_in[9];
  const float* dec_bhh = (const float*)d_in[10];
  const float* out_W   = (const float*)d_in[11];
  const float* out_b   = (const float*)d_in[12];
  const float* lin_W   = (const float*)d_in[13];
  const float* lin_b   = (const float*)d_in[14];
  float* dout = (float*)d_out;

  char* ws = (char*)d_ws;
  const size_t off_enc = 0;                                     // bf16 enc_out
  const size_t off_hp  = off_enc + (size_t)B_ * S_ * H_ * 2;    // 88,080,384
  const size_t off_hc  = off_hp + (size_t)2 * B_ * H_ * 4;      // hpack u32
  const size_t off_wb  = off_hc + (size_t)B_ * H_ * 4;
  const size_t off_ab  = off_wb + (size_t)768 * 512 * 2;
  const size_t off_fl  = off_ab + (size_t)36 * 336 * 8 * 2;
  const size_t need    = off_fl + 32 * S_ * sizeof(unsigned int);
  if (ws_size < need) return;

  bhalf* enc_out      = (bhalf*)(ws + off_enc);
  unsigned int* hpack = (unsigned int*)(ws + off_hp);
  float* hcur         = (float*)(ws + off_hc);
  bhalf* wb           = (bhalf*)(ws + off_wb);
  bhalf* abT          = (bhalf*)(ws + off_ab);
  unsigned int* flags = (unsigned int*)(ws + off_fl);

  (void)hipMemsetAsync(flags, 0, 32 * S_ * sizeof(unsigned int), stream);
  wpack_kernel<<<(768 * 512 + 255) / 256, 256, 0, stream>>>(dec_Whh, dec_Wih, wb);
  apack_kernel<<<(36 * 336 * 8 + 255) / 256, 256, 0, stream>>>(att_W, abT);
  enc_kernel<<<256, 128, 0, stream>>>(enc_Whh, enc_Wih, enc_bih, enc_bhh, xb,
                                      enc_out, hcur, hpack, flags);
  dec_kernel<<<B_ / 2, 512, 0, stream>>>(wb, abT, att_b, dec_bih, dec_bhh,
                                         out_W, out_b, lin_W, lin_b,
                                         enc_out, hcur, xb, dout);
}

// Round 9
// 4272.026 us; speedup vs baseline: 3.3150x; 1.2089x over previous
//
#include <hip/hip_runtime.h>
#include <cstdint>
#include <cstddef>

#define B_ 512
#define S_ 336
#define F_ 16
#define H_ 256
#define P_ 48

typedef __bf16 bhalf;
typedef __attribute__((ext_vector_type(8))) __bf16 bhalf8;
typedef __attribute__((ext_vector_type(4))) float f32x4;

#define MFMA16(A, Bv, C) __builtin_amdgcn_mfma_f32_16x16x32_bf16((A), (Bv), (C), 0, 0, 0)

__device__ __forceinline__ float fastrcp(float x) { return __builtin_amdgcn_rcpf(x); }
__device__ __forceinline__ float sigm(float x) { return fastrcp(1.0f + __expf(-x)); }
__device__ __forceinline__ float tanh_f(float x) { return 2.0f * fastrcp(1.0f + __expf(-2.0f * x)) - 1.0f; }

__device__ __forceinline__ bhalf u16_to_bf(unsigned int u) {
  return __builtin_bit_cast(__bf16, (unsigned short)u);
}
__device__ __forceinline__ unsigned short bf_to_u16(bhalf b) {
  return __builtin_bit_cast(unsigned short, b);
}

__device__ __forceinline__ bhalf8 bzero8() {
  bhalf8 v;
#pragma unroll
  for (int j = 0; j < 8; ++j) v[j] = (bhalf)0.0f;
  return v;
}

// ---------------------------------------------------------------------------
// Encoder: weight-stationary MFMA flag pipeline (verified r6-r8).
// CHANGES vs r8: (1) x A-frag load hoisted above the flag spin (prefetch);
// (2) enc_out stores moved AFTER the flag release — they have no consumer
// until dec_kernel launches (kernel-boundary ordering), so they drain at the
// NEXT step's barrier, overlapped with compute, off the critical path.
// ---------------------------------------------------------------------------
__global__ __launch_bounds__(128, 1) void enc_kernel(
    const float* __restrict__ Whh, const float* __restrict__ Wih,
    const float* __restrict__ bih, const float* __restrict__ bhh,
    const float* __restrict__ xb,        // [B][S][F] fp32
    bhalf* __restrict__ enc_out,         // [B][S][H]
    float* __restrict__ hcur,            // [B][H] final h, fp32 exact
    unsigned int* __restrict__ hpack,    // [2][B][H] relaxed-atomic channel
    unsigned int* __restrict__ flags)    // [32][S]
{
  __shared__ bhalf lds_lo[54 * 64 * 8];          // lo-plane B-frags, both waves
  const bhalf8* lds_v = (const bhalf8*)lds_lo;

  const int tid  = threadIdx.x;
  const int lane = tid & 63;
  const int wv   = tid >> 6;
  const int ncol = lane & 15;
  const int quad = lane >> 4;

  const int blk = blockIdx.x;
  const int g   = (blk & 7) * 4 + (blk >> 6);   // group 0..31
  const int w   = (blk >> 3) & 7;               // member 0..7
  const int b0  = g * 16;
  const int iw0 = w * 32;
  const int i0  = iw0 + wv * 16;

  // ---- lo-plane B-frags into LDS ----
  for (int it = tid; it < 54 * 64; it += 128) {
    const int fi = it >> 6;
    const int ln = it & 63;
    const int kt = fi % 9;
    const int rem = fi / 9;
    const int gg = rem % 3;
    const int wv2 = rem / 3;
    const int jrow = gg * 256 + iw0 + wv2 * 16 + (ln & 15);
    const int kbase = kt * 32 + ((ln >> 4) << 3);
    bhalf* dst = lds_lo + (size_t)it * 8;
#pragma unroll
    for (int j = 0; j < 8; ++j) {
      const int k = kbase + j;
      float v = 0.0f;
      if (k < 256) v = Whh[(size_t)jrow * 256 + k];
      else if (k < 272) v = Wih[(size_t)jrow * 16 + (k - 256)];
      const bhalf hi = (bhalf)v;
      dst[j] = (bhalf)(v - (float)hi);
    }
  }

  // ---- hi-plane B-frags in registers ----
  bhalf8 bWh[3][9];
#pragma unroll
  for (int gg = 0; gg < 3; ++gg) {
    const int jrow = gg * 256 + i0 + ncol;
#pragma unroll
    for (int kt = 0; kt < 9; ++kt) {
      bhalf8 v = bzero8();
      if (kt < 8) {
        const float* src = Whh + (size_t)jrow * 256 + kt * 32 + quad * 8;
#pragma unroll
        for (int j = 0; j < 8; ++j) v[j] = (bhalf)src[j];
      } else if (quad < 2) {
        const float* src = Wih + (size_t)jrow * 16 + quad * 8;
#pragma unroll
        for (int j = 0; j < 8; ++j) v[j] = (bhalf)src[j];
      }
      bWh[gg][kt] = v;
    }
  }

  const int jr = i0 + ncol;
  const float bR  = bih[jr]       + bhh[jr];
  const float bZ  = bih[256 + jr] + bhh[256 + jr];
  const float bNx = bih[512 + jr];
  const float bNh = bhh[512 + jr];

  __syncthreads();

  const int bA = b0 + ncol;
  const int kA = quad * 8;

  float hold[4] = {0.0f, 0.0f, 0.0f, 0.0f};

  for (int t = 0; t < S_; ++t) {
    // x prefetch (independent of flags) — issue before the spin
    bhalf8 xh = bzero8(), xl = bzero8();
    if (quad < 2) {
      const float* xp = xb + ((size_t)bA * S_ + t) * F_ + quad * 8;
#pragma unroll
      for (int j = 0; j < 8; ++j) {
        const float v = xp[j];
        const bhalf h = (bhalf)v;
        xh[j] = h;
        xl[j] = (bhalf)(v - (float)h);
      }
    }

    if (t > 0) {
      unsigned int* fp = &flags[g * S_ + (t - 1)];
      if (tid == 0) {
        while (__hip_atomic_load(fp, __ATOMIC_RELAXED, __HIP_MEMORY_SCOPE_AGENT) < 8u)
          __builtin_amdgcn_s_sleep(1);
      }
      __syncthreads();
    }

    f32x4 aR0 = {0,0,0,0}, aR1 = {0,0,0,0}, aR2 = {0,0,0,0};
    f32x4 aZ0 = {0,0,0,0}, aZ1 = {0,0,0,0}, aZ2 = {0,0,0,0};
    f32x4 aN0 = {0,0,0,0}, aN1 = {0,0,0,0}, aN2 = {0,0,0,0};
    f32x4 aNx = {0,0,0,0};

    if (t > 0) {
      const int slot = (t - 1) & 1;
      const unsigned long long* hp64 =
          (const unsigned long long*)(hpack + ((size_t)slot * B_ + bA) * H_ + kA);
#pragma unroll
      for (int kt = 0; kt < 8; ++kt) {
        bhalf8 Ah, Al;
#pragma unroll
        for (int j2 = 0; j2 < 4; ++j2) {
          const unsigned long long w2 =
              __hip_atomic_load(hp64 + kt * 16 + j2, __ATOMIC_RELAXED,
                                __HIP_MEMORY_SCOPE_AGENT);
          Ah[2 * j2]     = u16_to_bf((unsigned int)w2);
          Al[2 * j2]     = u16_to_bf((unsigned int)(w2 >> 16));
          Ah[2 * j2 + 1] = u16_to_bf((unsigned int)(w2 >> 32));
          Al[2 * j2 + 1] = u16_to_bf((unsigned int)(w2 >> 48));
        }
        const bhalf8 wl0 = lds_v[((wv * 3 + 0) * 9 + kt) * 64 + lane];
        const bhalf8 wl1 = lds_v[((wv * 3 + 1) * 9 + kt) * 64 + lane];
        const bhalf8 wl2 = lds_v[((wv * 3 + 2) * 9 + kt) * 64 + lane];
        aR0 = MFMA16(Ah, bWh[0][kt], aR0);
        aR1 = MFMA16(Ah, wl0, aR1);
        aR2 = MFMA16(Al, bWh[0][kt], aR2);
        aZ0 = MFMA16(Ah, bWh[1][kt], aZ0);
        aZ1 = MFMA16(Ah, wl1, aZ1);
        aZ2 = MFMA16(Al, bWh[1][kt], aZ2);
        aN0 = MFMA16(Ah, bWh[2][kt], aN0);
        aN1 = MFMA16(Ah, wl2, aN1);
        aN2 = MFMA16(Al, bWh[2][kt], aN2);
      }
    }
    {  // kt = 8: x-part (R/Z join gate accs; N x-part separate)
      const bhalf8 wl0 = lds_v[((wv * 3 + 0) * 9 + 8) * 64 + lane];
      const bhalf8 wl1 = lds_v[((wv * 3 + 1) * 9 + 8) * 64 + lane];
      const bhalf8 wl2 = lds_v[((wv * 3 + 2) * 9 + 8) * 64 + lane];
      aR0 = MFMA16(xh, bWh[0][8], aR0);
      aR1 = MFMA16(xh, wl0, aR1);
      aR2 = MFMA16(xl, bWh[0][8], aR2);
      aZ0 = MFMA16(xh, bWh[1][8], aZ0);
      aZ1 = MFMA16(xh, wl1, aZ1);
      aZ2 = MFMA16(xl, bWh[1][8], aZ2);
      aNx = MFMA16(xh, bWh[2][8], aNx);
      aNx = MFMA16(xh, wl2, aNx);
      aNx = MFMA16(xl, bWh[2][8], aNx);
    }

    // ---- gates (C/D: col = lane&15, row = quad*4 + reg) ----
    const int iL = i0 + ncol;
    bhalf his[4], los[4];
#pragma unroll
    for (int r = 0; r < 4; ++r) {
      const float sR  = aR0[r] + aR1[r] + aR2[r] + bR;
      const float sZ  = aZ0[r] + aZ1[r] + aZ2[r] + bZ;
      const float nhv = aN0[r] + aN1[r] + aN2[r] + bNh;
      const float nxv = aNx[r] + bNx;
      const float rr = sigm(sR);
      const float zz = sigm(sZ);
      const float nn = tanh_f(nxv + rr * nhv);
      const float h2 = (1.0f - zz) * nn + zz * hold[r];
      hold[r] = h2;
      his[r] = (bhalf)h2;
      los[r] = (bhalf)(h2 - (float)his[r]);
      const int bb = b0 + quad * 4 + r;
      const unsigned int wrd =
          (unsigned int)bf_to_u16(his[r]) | ((unsigned int)bf_to_u16(los[r]) << 16);
      __hip_atomic_store(&hpack[((size_t)(t & 1) * B_ + bb) * H_ + iL], wrd,
                         __ATOMIC_RELAXED, __HIP_MEMORY_SCOPE_AGENT);
    }

    __syncthreads();   // drains vmcnt(0): hpack stores visible before flag
    if (tid == 0) {
      __hip_atomic_fetch_add(&flags[g * S_ + t], 1u, __ATOMIC_RELAXED,
                             __HIP_MEMORY_SCOPE_AGENT);
    }

    // enc_out stores AFTER release: no consumer until dec_kernel (kernel
    // boundary orders); they drain at the next step's barrier, overlapped.
#pragma unroll
    for (int r = 0; r < 4; ++r) {
      const int bb = b0 + quad * 4 + r;
      enc_out[((size_t)bb * S_ + t) * H_ + iL] = his[r];
    }
  }

#pragma unroll
  for (int r = 0; r < 4; ++r)
    hcur[(size_t)(b0 + quad * 4 + r) * H_ + i0 + ncol] = hold[r];
}

// ---------------------------------------------------------------------------
// Prep: dec GRU weights -> TRANSPOSED bf16 pack wbT[64][768][8]:
// wbT[k8][row][j] = (k8*8+j < 256) ? Whh[row][k8*8+j] : Wih[row][k8*8+j-256]
// Lane-consecutive rows -> coalesced 16-B loads in the decoder GRU.
// ---------------------------------------------------------------------------
__global__ __launch_bounds__(256) void wpack_kernel(const float* __restrict__ Whh,
                                                    const float* __restrict__ Wih,
                                                    bhalf* __restrict__ wbT) {
  const int idx = blockIdx.x * 256 + threadIdx.x;
  if (idx >= 64 * 768 * 8) return;
  const int j = idx & 7;
  const int row = (idx >> 3) % 768;
  const int k8 = idx / (768 * 8);
  const int k = k8 * 8 + j;
  const float v = (k < 256) ? Whh[(size_t)row * 256 + k]
                            : Wih[(size_t)row * 256 + (k - 256)];
  wbT[idx] = (bhalf)v;
}

// ---------------------------------------------------------------------------
// Prep: attW -> bf16 TRANSPOSED pack abT[36][336][8] (zero-padded k>=272)
// ---------------------------------------------------------------------------
__global__ __launch_bounds__(256) void apack_kernel(const float* __restrict__ attW,
                                                    bhalf* __restrict__ abT) {
  const int idx = blockIdx.x * 256 + threadIdx.x;
  if (idx >= 36 * 336 * 8) return;
  const int j = idx & 7;
  const int s = (idx >> 3) % 336;
  const int k8 = idx / (8 * 336);
  const int k = k8 * 8 + j;
  abT[idx] = (k < 272) ? (bhalf)attW[(size_t)s * 272 + k] : (bhalf)0.0f;
}

// ---------------------------------------------------------------------------
// Decoder: ONE fused kernel, all 48 steps. CHANGE vs r8: DR=1 — 512 blocks
// x 256 threads = 2 blocks/CU (co-resident blocks overlap each other's
// memory stalls); GRU accumulates fully in registers (no K-split LDS
// round-trip, 2 fewer barriers); transposed coalesced GRU weights; padded
// pC (no bank conflicts); softmax/out phases use more threads.
// ---------------------------------------------------------------------------
__global__ __launch_bounds__(256) void dec_kernel(
    const bhalf* __restrict__ wbT,      // [64][768][8]
    const bhalf* __restrict__ abT,      // [36][336][8]
    const float* __restrict__ attb,
    const float* __restrict__ bih, const float* __restrict__ bhh,
    const float* __restrict__ outW, const float* __restrict__ outb,
    const float* __restrict__ linW, const float* __restrict__ linb,
    const bhalf* __restrict__ enc_out, const float* __restrict__ hcur,
    const float* __restrict__ xb, float* __restrict__ dout)
{
  __shared__ float hyL[288];        // [h(256) | y(16) | 0-pad(16)]
  __shared__ float cL[256];
  __shared__ float sc[S_];
  __shared__ float pC[8][32][9];    // combine partials, padded (bank-safe)
  __shared__ float oP[4][16];
  __shared__ float oF[16];
  __shared__ float red[8];
  const int tid  = threadIdx.x;
  const int lane = tid & 63;
  const int wv   = tid >> 6;
  const int b    = blockIdx.x;
  const int jj   = tid;
  const int cg   = tid & 31;        // combine col-group (8 cols)
  const int ck   = tid >> 5;        // combine s-chunk (42 s)

  hyL[tid] = hcur[(size_t)b * H_ + tid];
  if (tid < 16) hyL[256 + tid] = xb[((size_t)b * S_ + (S_ - 1)) * F_ + tid];
  else if (tid < 32) hyL[256 + tid] = 0.0f;

  const float bRv  = bih[jj]       + bhh[jj];
  const float bZv  = bih[256 + jj] + bhh[256 + jj];
  const float bNxv = bih[512 + jj];
  const float bNhv = bhh[512 + jj];

  const bhalf* epC = enc_out + ((size_t)b * S_ + ck * 42) * H_ + cg * 8;
  __syncthreads();

  for (int p = 0; p < P_; ++p) {
    // ---- attention scores (coalesced bf16 weights) ----
    for (int s = tid; s < S_; s += 256) {
      float d0 = 0, d1 = 0, d2 = 0, d3 = 0;
#pragma unroll 4
      for (int k8 = 0; k8 < 36; ++k8) {
        const bhalf8 q = *(const bhalf8*)(abT + ((size_t)k8 * S_ + s) * 8);
        const float* v = hyL + k8 * 8;
        d0 += (float)q[0] * v[0] + (float)q[4] * v[4];
        d1 += (float)q[1] * v[1] + (float)q[5] * v[5];
        d2 += (float)q[2] * v[2] + (float)q[6] * v[6];
        d3 += (float)q[3] * v[3] + (float)q[7] * v[7];
      }
      sc[s] = d0 + d1 + d2 + d3 + attb[s];
    }
    __syncthreads();

    // ---- softmax (all 4 waves) ----
    float mx = -3e38f;
    for (int s = tid; s < S_; s += 256) mx = fmaxf(mx, sc[s]);
#pragma unroll
    for (int o = 32; o > 0; o >>= 1) mx = fmaxf(mx, __shfl_xor(mx, o, 64));
    if (lane == 0) red[wv] = mx;
    __syncthreads();
    mx = fmaxf(fmaxf(red[0], red[1]), fmaxf(red[2], red[3]));
    float sum = 0.0f;
    for (int s = tid; s < S_; s += 256) {
      const float e = __expf(sc[s] - mx);
      sc[s] = e;
      sum += e;
    }
#pragma unroll
    for (int o = 32; o > 0; o >>= 1) sum += __shfl_xor(sum, o, 64);
    if (lane == 0) red[4 + wv] = sum;
    __syncthreads();
    const float inv = fastrcp(red[4] + red[5] + red[6] + red[7]);
    for (int s = tid; s < S_; s += 256) sc[s] *= inv;
    __syncthreads();

    // ---- combine: thread (ck, cg), 42 x 16-B loads ----
    {
      float a0 = 0, a1 = 0, a2 = 0, a3 = 0, a4 = 0, a5 = 0, a6 = 0, a7 = 0;
      const float* scrow = sc + ck * 42;
#pragma unroll 6
      for (int s5 = 0; s5 < 42; ++s5) {
        const bhalf8 v = *(const bhalf8*)(epC + (size_t)s5 * H_);
        const float wgt = scrow[s5];
        a0 += wgt * (float)v[0];
        a1 += wgt * (float)v[1];
        a2 += wgt * (float)v[2];
        a3 += wgt * (float)v[3];
        a4 += wgt * (float)v[4];
        a5 += wgt * (float)v[5];
        a6 += wgt * (float)v[6];
        a7 += wgt * (float)v[7];
      }
      float* pp = pC[ck][cg];
      pp[0] = a0; pp[1] = a1; pp[2] = a2; pp[3] = a3;
      pp[4] = a4; pp[5] = a5; pp[6] = a6; pp[7] = a7;
    }
    __syncthreads();
    {
      float s = 0.0f;
      const int gg = jj >> 3, j = jj & 7;
#pragma unroll
      for (int c = 0; c < 8; ++c) s += pC[c][gg][j];
      cL[jj] = s;
    }
    __syncthreads();

    // ---- GRU: full-K in registers (rows jj, 256+jj, 512+jj of wbT) ----
    float hnew;
    {
      float r0 = 0, r1 = 0, z0 = 0, z1 = 0, nh0 = 0, nh1 = 0, nx0 = 0, nx1 = 0;
#pragma unroll 4
      for (int k8 = 0; k8 < 32; ++k8) {          // h part
        const bhalf* base = wbT + ((size_t)k8 * 768) * 8;
        const bhalf8 qR = *(const bhalf8*)(base + (size_t)jj * 8);
        const bhalf8 qZ = *(const bhalf8*)(base + (size_t)(256 + jj) * 8);
        const bhalf8 qN = *(const bhalf8*)(base + (size_t)(512 + jj) * 8);
        const float* v = hyL + k8 * 8;
        r0 += (float)qR[0]*v[0] + (float)qR[2]*v[2] + (float)qR[4]*v[4] + (float)qR[6]*v[6];
        r1 += (float)qR[1]*v[1] + (float)qR[3]*v[3] + (float)qR[5]*v[5] + (float)qR[7]*v[7];
        z0 += (float)qZ[0]*v[0] + (float)qZ[2]*v[2] + (float)qZ[4]*v[4] + (float)qZ[6]*v[6];
        z1 += (float)qZ[1]*v[1] + (float)qZ[3]*v[3] + (float)qZ[5]*v[5] + (float)qZ[7]*v[7];
        nh0 += (float)qN[0]*v[0] + (float)qN[2]*v[2] + (float)qN[4]*v[4] + (float)qN[6]*v[6];
        nh1 += (float)qN[1]*v[1] + (float)qN[3]*v[3] + (float)qN[5]*v[5] + (float)qN[7]*v[7];
      }
#pragma unroll 4
      for (int k8 = 32; k8 < 64; ++k8) {         // c part
        const bhalf* base = wbT + ((size_t)k8 * 768) * 8;
        const bhalf8 qR = *(const bhalf8*)(base + (size_t)jj * 8);
        const bhalf8 qZ = *(const bhalf8*)(base + (size_t)(256 + jj) * 8);
        const bhalf8 qN = *(const bhalf8*)(base + (size_t)(512 + jj) * 8);
        const float* v = cL + (k8 - 32) * 8;
        r0 += (float)qR[0]*v[0] + (float)qR[2]*v[2] + (float)qR[4]*v[4] + (float)qR[6]*v[6];
        r1 += (float)qR[1]*v[1] + (float)qR[3]*v[3] + (float)qR[5]*v[5] + (float)qR[7]*v[7];
        z0 += (float)qZ[0]*v[0] + (float)qZ[2]*v[2] + (float)qZ[4]*v[4] + (float)qZ[6]*v[6];
        z1 += (float)qZ[1]*v[1] + (float)qZ[3]*v[3] + (float)qZ[5]*v[5] + (float)qZ[7]*v[7];
        nx0 += (float)qN[0]*v[0] + (float)qN[2]*v[2] + (float)qN[4]*v[4] + (float)qN[6]*v[6];
        nx1 += (float)qN[1]*v[1] + (float)qN[3]*v[3] + (float)qN[5]*v[5] + (float)qN[7]*v[7];
      }
      const float sR = r0 + r1 + bRv;
      const float sZ = z0 + z1 + bZv;
      const float nh = nh0 + nh1 + bNhv;
      const float nx = nx0 + nx1 + bNxv;
      const float rr = 1.0f / (1.0f + __expf(-sR));
      const float zz = 1.0f / (1.0f + __expf(-sZ));
      const float nn = tanhf(nx + rr * nh);
      hnew = (1.0f - zz) * nn + zz * hyL[jj];
    }
    __syncthreads();   // all hyL reads complete
    hyL[jj] = hnew;
    __syncthreads();

    // ---- out: 64 threads, 4-way K split ----
    if (tid < 64) {
      const int f = tid & 15, q = tid >> 4;
      const float* wr = outW + (size_t)f * H_ + q * 64;
      const float* hv = hyL + q * 64;
      float a0 = 0, a1 = 0, a2 = 0, a3 = 0;
#pragma unroll 4
      for (int k = 0; k < 64; k += 4) {
        a0 += wr[k]     * hv[k];
        a1 += wr[k + 1] * hv[k + 1];
        a2 += wr[k + 2] * hv[k + 2];
        a3 += wr[k + 3] * hv[k + 3];
      }
      oP[q][f] = a0 + a1 + a2 + a3;
    }
    __syncthreads();
    if (tid < 16) {
      const float o = oP[0][tid] + oP[1][tid] + oP[2][tid] + oP[3][tid] + outb[tid];
      oF[tid] = o;
      hyL[256 + tid] = o;    // y feedback
    }
    __syncthreads();
    if (tid == 0) {
      float pr = linb[0];
#pragma unroll
      for (int f = 0; f < 16; ++f) pr += oF[f] * linW[f];
      dout[(size_t)b * P_ + p] = pr;
    }
  }
}

// ---------------------------------------------------------------------------
extern "C" void kernel_launch(void* const* d_in, const int* in_sizes, int n_in,
                              void* d_out, int out_size, void* d_ws, size_t ws_size,
                              hipStream_t stream)
{
  (void)in_sizes; (void)n_in; (void)out_size;
  const float* xb      = (const float*)d_in[0];
  const float* enc_Wih = (const float*)d_in[1];
  const float* enc_Whh = (const float*)d_in[2];
  const float* enc_bih = (const float*)d_in[3];
  const float* enc_bhh = (const float*)d_in[4];
  const float* att_W   = (const float*)d_in[5];
  const float* att_b   = (const float*)d_in[6];
  const float* dec_Wih = (const float*)d_in[7];
  const float* dec_Whh = (const float*)d_in[8];
  const float* dec_bih = (const float*)d_in[9];
  const float* dec_bhh = (const float*)d_in[10];
  const float* out_W   = (const float*)d_in[11];
  const float* out_b   = (const float*)d_in[12];
  const float* lin_W   = (const float*)d_in[13];
  const float* lin_b   = (const float*)d_in[14];
  float* dout = (float*)d_out;

  char* ws = (char*)d_ws;
  const size_t off_enc = 0;                                     // bf16 enc_out
  const size_t off_hp  = off_enc + (size_t)B_ * S_ * H_ * 2;    // 88,080,384
  const size_t off_hc  = off_hp + (size_t)2 * B_ * H_ * 4;      // hpack u32
  const size_t off_wb  = off_hc + (size_t)B_ * H_ * 4;
  const size_t off_ab  = off_wb + (size_t)64 * 768 * 8 * 2;
  const size_t off_fl  = off_ab + (size_t)36 * 336 * 8 * 2;
  const size_t need    = off_fl + 32 * S_ * sizeof(unsigned int);
  if (ws_size < need) return;

  bhalf* enc_out      = (bhalf*)(ws + off_enc);
  unsigned int* hpack = (unsigned int*)(ws + off_hp);
  float* hcur         = (float*)(ws + off_hc);
  bhalf* wbT          = (bhalf*)(ws + off_wb);
  bhalf* abT          = (bhalf*)(ws + off_ab);
  unsigned int* flags = (unsigned int*)(ws + off_fl);

  (void)hipMemsetAsync(flags, 0, 32 * S_ * sizeof(unsigned int), stream);
  wpack_kernel<<<(64 * 768 * 8 + 255) / 256, 256, 0, stream>>>(dec_Whh, dec_Wih, wbT);
  apack_kernel<<<(36 * 336 * 8 + 255) / 256, 256, 0, stream>>>(att_W, abT);
  enc_kernel<<<256, 128, 0, stream>>>(enc_Whh, enc_Wih, enc_bih, enc_bhh, xb,
                                      enc_out, hcur, hpack, flags);
  dec_kernel<<<B_, 256, 0, stream>>>(wbT, abT, att_b, dec_bih, dec_bhh,
                                     out_W, out_b, lin_W, lin_b,
                                     enc_out, hcur, xb, dout);
}